// Round 11
// baseline (258.866 us; speedup 1.0000x reference)
//
#include <hip/hip_runtime.h>
#include <math.h>

#define NB 8
#define NC 96
#define NH 128
#define NWID 128
#define NN (NH*NWID)      // 16384
#define NCO 192
#define NM (NC*NN)        // 1572864

// ---------------- workspace layout (float offsets) ----------------
#define WS_SUMS   0                     // [2][8][2]  (zeroed)
#define WS_SC     32                    // [8][32][32] (zeroed)
#define WS_AC     8224                  // [8][32][32]
#define WS_SU     16416                 // [8][96]
#define WS_TU     17184
#define WS_SD     17952
#define WS_TD     18720
#define WS_RU     19488                 // resc_u [8][96]
#define WS_RD     20256                 // resc_d
#define WS_CADD   21024                 // rebias_u+rebias_d
#define WS_BPU    21792                 // eff bias [8][192]
#define WS_BPD    23328
#define WS_QKV16  327680                // ushort region: 2 tensors x 25165824 u16 (bf16 qkv; only ch 64..127,160..191 valid)
#define QKV16_D   25165824ull
#define WS_SLABS  25493504              // ushort region base: mfma-ready slabs (PACKED rows)
#define SLAB_SZ   4194304ull            // 8*128*128*32 u16 each
#define OFF_QH    (0*SLAB_SZ)           // [8][128w][128h][32c]
#define OFF_KH    (1*SLAB_SZ)
#define OFF_QW    (2*SLAB_SZ)           // [8][128h][128w][32c]
#define OFF_KW    (3*SLAB_SZ)
#define OFF_VHU   (4*SLAB_SZ)           // [8][128w][32c][128h]
#define OFF_VHD   (5*SLAB_SZ)
#define OFF_VWU   (6*SLAB_SZ)           // [8][128h][32c][128w]
#define OFF_VWD   (7*SLAB_SZ)
#define WS_OH     44892160              // bf16 [8][128w][32c][128h] h-attn staging (ushort region)

typedef __attribute__((ext_vector_type(8))) short bf16x8;
typedef __attribute__((ext_vector_type(4))) float f32x4;

static __device__ __forceinline__ float bf2f(ushort u){ return __uint_as_float(((uint)u) << 16); }
static __device__ __forceinline__ ushort f2bf(float f){
  uint b = __float_as_uint(f);
  return (ushort)((b + 0x7fffu + ((b >> 16) & 1u)) >> 16);
}
static __device__ __forceinline__ bf16x8 ldfrag(const ushort* p){
  union { uint4 u; bf16x8 b; } cv; cv.u = *(const uint4*)p; return cv.b;
}

// ---------------- stats reduction: per-sample sum & sumsq ----------------
__global__ __launch_bounds__(256) void reduce_stats(const float* __restrict__ xu,
                                                    const float* __restrict__ xd,
                                                    float* __restrict__ ws) {
  int blk = blockIdx.x;                // 2*8*64
  int tensor = blk >> 9;
  int b = (blk >> 6) & 7;
  int chunk = blk & 63;
  const float* x = tensor ? xd : xu;
  const float4* p = (const float4*)(x + (size_t)b*NM + (size_t)chunk*(NM/64));
  float s = 0.f, sq = 0.f;
  for (int r = 0; r < 24; r++) {
    float4 v = p[threadIdx.x + r*256];
    s  += v.x + v.y + v.z + v.w;
    sq += v.x*v.x + v.y*v.y + v.z*v.z + v.w*v.w;
  }
  for (int o = 32; o; o >>= 1) { s += __shfl_down(s, o); sq += __shfl_down(sq, o); }
  __shared__ float ls[8];
  int wv = threadIdx.x >> 6, ln = threadIdx.x & 63;
  if (ln == 0) { ls[wv*2] = s; ls[wv*2+1] = sq; }
  __syncthreads();
  if (threadIdx.x == 0) {
    s  = ls[0] + ls[2] + ls[4] + ls[6];
    sq = ls[1] + ls[3] + ls[5] + ls[7];
    atomicAdd(&ws[WS_SUMS + (tensor*8 + b)*2],     s);
    atomicAdd(&ws[WS_SUMS + (tensor*8 + b)*2 + 1], sq);
  }
}

// ---------------- derived params ----------------
__global__ void compute_params(float* __restrict__ ws,
    const float* __restrict__ nwu, const float* __restrict__ nbu,
    const float* __restrict__ m1wu, const float* __restrict__ m1bu,
    const float* __restrict__ m2wu, const float* __restrict__ m2bu,
    const float* __restrict__ nwd, const float* __restrict__ nbd,
    const float* __restrict__ m1wd, const float* __restrict__ m1bd,
    const float* __restrict__ m2wd, const float* __restrict__ m2bd,
    const float* __restrict__ Wqu, const float* __restrict__ bqu,
    const float* __restrict__ Wqd, const float* __restrict__ bqd) {
  __shared__ float meanL[16], stdL[16];
  __shared__ float tuL[768], tdL[768];
  int t = threadIdx.x;
  if (t < 16) {
    float s = ws[WS_SUMS + t*2], sq = ws[WS_SUMS + t*2 + 1];
    const float inv = 1.f / (float)NM;
    float mean = s * inv;
    float var  = sq * inv - mean*mean;
    meanL[t] = mean;
    stdL[t]  = sqrtf(var + 1e-5f);
  }
  __syncthreads();
  for (int idx = t; idx < 768; idx += 256) {
    int b = idx / 96, c = idx % 96;
    float mu = meanL[b],   su = stdL[b];
    float md = meanL[8+b], sd = stdL[8+b];
    float scu = nwu[c] / su;
    float scd = nwd[c] / sd;
    float tcu = nbu[c] - mu*scu;
    float tcd = nbd[c] - md*scd;
    tuL[idx] = tcu; tdL[idx] = tcd;
    ws[WS_SU+idx] = scu; ws[WS_TU+idx] = tcu;
    ws[WS_SD+idx] = scd; ws[WS_TD+idx] = tcd;
    ws[WS_RU+idx] = su*m1wu[c] + m1bu[c];
    ws[WS_RD+idx] = sd*m1wd[c] + m1bd[c];
    ws[WS_CADD+idx] = (mu*m2wu[c] + m2bu[c]) + (md*m2wd[c] + m2bd[c]);
  }
  __syncthreads();
  for (int idx = t; idx < 3072; idx += 256) {
    int tensor = idx / 1536;
    int r = idx % 1536;
    int b = r / 192, o = r % 192;
    const float* Wq = tensor ? Wqd : Wqu;
    const float* tt = tensor ? tdL : tuL;
    float acc = tensor ? bqd[o] : bqu[o];
    for (int i = 0; i < 96; i++) acc += Wq[o*96 + i] * tt[b*96 + i];
    ws[(tensor ? WS_BPD : WS_BPU) + r] = acc;
  }
}

// ---------------- qkv GEMM via MFMA + fused slab epilogue ----------------
// 64-wide n-tiles; A-stage converts raw W (fp32, L2-hot) * scale -> bf16 in LDS.
__global__ __launch_bounds__(256) void qkv_gemm(float* __restrict__ ws,
    const float* __restrict__ xu, const float* __restrict__ xd,
    const float* __restrict__ Wqu, const float* __restrict__ Wqd) {
  __shared__ __align__(16) ushort QL[16640];   // 33280 B
  ushort* Bl = QL;                 // [64][104] u16 = 6656
  ushort* Ah = QL + 6656;          // [96][104] u16 = 9984
  int blk = blockIdx.x;                 // 2 tensor * 8 b * 128 h * 2 wh
  int tensor = blk >> 11;
  int rem = blk & 2047;
  int b = rem >> 8;
  int r2 = rem & 255;
  int nt = r2 >> 1;                     // h
  int wh = r2 & 1;                      // 64-col half
  int n0 = nt*128 + wh*64;
  const float* x = (tensor ? xd : xu) + (size_t)b*NM;
  const float* Wq = tensor ? Wqd : Wqu;
  const float* sca = ws + (tensor ? WS_SD : WS_SU) + b*96;
  const float* bp = ws + (tensor ? WS_BPD : WS_BPU) + b*192;
  ushort* outq16 = (ushort*)(ws + WS_QKV16) + (tensor ? QKV16_D : 0) + (size_t)b*NCO*NN;
  ushort* slab = (ushort*)(ws + WS_SLABS);
  const int t = threadIdx.x;
  const int wv = t >> 6, lid = t & 63, l15 = lid & 15, l4 = lid >> 4;

  // stage B: X^T bf16 [64][104]; 768 tasks (i2 0..47, n4 0..15)
  for (int it = 0; it < 3; it++) {
    int idx = t + it*256;
    int i2 = (idx & 7) | ((idx >> 7) << 3);
    int n4 = (idx >> 3) & 15;
    const float* r0 = x + (size_t)(2*i2)*NN + n0 + n4*4;
    float4 a0 = *(const float4*)r0;
    float4 a1 = *(const float4*)(r0 + NN);
    uint p0 = (uint)f2bf(a0.x) | ((uint)f2bf(a1.x) << 16);
    uint p1 = (uint)f2bf(a0.y) | ((uint)f2bf(a1.y) << 16);
    uint p2 = (uint)f2bf(a0.z) | ((uint)f2bf(a1.z) << 16);
    uint p3 = (uint)f2bf(a0.w) | ((uint)f2bf(a1.w) << 16);
    ushort* base = &Bl[(size_t)(n4*4)*104 + 2*i2];
    *(uint*)(base)           = p0;
    *(uint*)(base + 104)     = p1;
    *(uint*)(base + 208)     = p2;
    *(uint*)(base + 312)     = p3;
  }
  // stage A half 0 (W rows 0..95): 4608 pair-tasks, convert fp32*scale -> bf16
  for (int it = 0; it < 18; it++) {
    int idx = t + it*256;
    int o = idx / 48, ip = idx % 48;
    float2 wv2 = *(const float2*)(Wq + (size_t)o*96 + 2*ip);
    float2 sv  = *(const float2*)(sca + 2*ip);
    *(uint*)&Ah[o*104 + 2*ip] = (uint)f2bf(wv2.x*sv.x) | ((uint)f2bf(wv2.y*sv.y) << 16);
  }
  __syncthreads();

  // hoist B fragments (wave wv owns cols wv*16..wv*16+15)
  bf16x8 bfr[3];
  #pragma unroll
  for (int s = 0; s < 3; s++)
    bfr[s] = ldfrag(&Bl[(wv*16 + l15)*104 + s*32 + l4*8]);

  f32x4 z4 = {0.f,0.f,0.f,0.f};
  f32x4 acc[12];
  #pragma unroll
  for (int mt = 0; mt < 12; mt++) acc[mt] = z4;
  // half 0: output rows 0..95
  #pragma unroll
  for (int s = 0; s < 3; s++) {
    #pragma unroll
    for (int mt = 0; mt < 6; mt++) {
      bf16x8 a = ldfrag(&Ah[(mt*16 + l15)*104 + s*32 + l4*8]);
      acc[mt] = __builtin_amdgcn_mfma_f32_16x16x32_bf16(a, bfr[s], acc[mt], 0, 0, 0);
    }
  }
  __syncthreads();
  // stage A half 1 (W rows 96..191)
  for (int it = 0; it < 18; it++) {
    int idx = t + it*256;
    int o = idx / 48, ip = idx % 48;
    float2 wv2 = *(const float2*)(Wq + (size_t)(96 + o)*96 + 2*ip);
    float2 sv  = *(const float2*)(sca + 2*ip);
    *(uint*)&Ah[o*104 + 2*ip] = (uint)f2bf(wv2.x*sv.x) | ((uint)f2bf(wv2.y*sv.y) << 16);
  }
  __syncthreads();
  #pragma unroll
  for (int s = 0; s < 3; s++) {
    #pragma unroll
    for (int mt = 0; mt < 6; mt++) {
      bf16x8 a = ldfrag(&Ah[(mt*16 + l15)*104 + s*32 + l4*8]);
      acc[6+mt] = __builtin_amdgcn_mfma_f32_16x16x32_bf16(a, bfr[s], acc[6+mt], 0, 0, 0);
    }
  }
  __syncthreads();       // all LDS reads done; reuse QL as C bounce [192][72] u16
  ushort* Cl = QL;
  #pragma unroll
  for (int mt = 0; mt < 12; mt++) {
    #pragma unroll
    for (int r = 0; r < 4; r++) {
      int o = mt*16 + l4*4 + r;
      Cl[o*72 + wv*16 + l15] = f2bf(acc[mt][r] + bp[o]);
    }
  }
  __syncthreads();
  // (1) qkv16 store, 96 channels {64..127, 160..191}: 768 uint4
  for (int it = 0; it < 3; it++) {
    int idx = t + it*256;
    int lr = idx >> 3, ch = idx & 7;
    int o = (lr < 64) ? (64 + lr) : (96 + lr);
    *(uint4*)(outq16 + (size_t)o*NN + n0 + ch*8) = *(const uint4*)&Cl[o*72 + ch*8];
  }
  // (2) Q/K h- and w-slabs (PACKED 32c rows): 128 tasks
  if (t < 128) {
    int axis = t >> 6, w = t & 63;
    ushort* dstq = slab + (tensor ? (axis ? OFF_KW : OFF_KH) : (axis ? OFF_QW : OFF_QH));
    size_t o = axis ? ((size_t)(b*128 + nt)*128 + wh*64 + w)*32
                    : ((size_t)(b*128 + wh*64 + w)*128 + nt)*32;
    uint uu[16];
    #pragma unroll
    for (int k = 0; k < 16; k++) {
      ushort a0 = Cl[(axis*32 + 2*k)*72 + w];
      ushort a1 = Cl[(axis*32 + 2*k + 1)*72 + w];
      uu[k] = (uint)a0 | ((uint)a1 << 16);
    }
    *(uint4*)(dstq + o)      = make_uint4(uu[0],uu[1],uu[2],uu[3]);
    *(uint4*)(dstq + o + 8)  = make_uint4(uu[4],uu[5],uu[6],uu[7]);
    *(uint4*)(dstq + o + 16) = make_uint4(uu[8],uu[9],uu[10],uu[11]);
    *(uint4*)(dstq + o + 24) = make_uint4(uu[12],uu[13],uu[14],uu[15]);
  }
  // (3) VW slab (ch 128..159, PACKED 128w rows): 256 uint4 tasks
  {
    ushort* dstv = slab + (tensor ? OFF_VWD : OFF_VWU);
    int c = t >> 3, ch = t & 7;
    *(uint4*)(dstv + ((size_t)(b*128 + nt)*32 + c)*128 + wh*64 + ch*8) =
        *(const uint4*)&Cl[(128 + c)*72 + ch*8];
  }
}

// ---------------- prep: VH slabs only (ch 96..127 -> [b][w][32c][128h] packed) ----------------
__global__ __launch_bounds__(256) void qkv_prep(float* __restrict__ ws) {
  __shared__ __align__(16) ushort Br[16*1320];   // [16c][33h][40w] c-stride 1320
  int bid = blockIdx.x;                           // 2 tensor * 2cb * 8b * 4hb * 4wb = 512
  int tensor = bid >> 8;
  int r = bid & 255;
  int cb = r >> 7, b = (r >> 4) & 7, hb = (r >> 2) & 3, wb = r & 3;
  const ushort* qkv16 = (const ushort*)(ws + WS_QKV16);
  const ushort* src = qkv16 + (tensor ? QKV16_D : 0)
                    + (size_t)b*NCO*NN + (size_t)(96 + cb*16)*NN;
  ushort* dst = (ushort*)(ws + WS_SLABS) + (tensor ? OFF_VHD : OFF_VHU);
  int t = threadIdx.x;
  for (int k = 0; k < 8; k++) {
    int idx = t + k*256;                          // 2048 = 16c*32h*4(w8)
    int c = idx >> 7, h = (idx >> 2) & 31, w8 = idx & 3;
    uint4 v = *(const uint4*)(src + (size_t)c*NN + (size_t)(hb*32 + h)*NWID + wb*32 + w8*8);
    *(uint4*)&Br[c*1320 + h*40 + w8*8] = v;
  }
  __syncthreads();
  for (int k = 0; k < 2; k++) {
    int idx = t + k*256;                          // 512 = 32w*16c
    int w = idx >> 4, c = idx & 15;
    uint uu[16];
    #pragma unroll
    for (int hh = 0; hh < 16; hh++) {
      ushort a0 = Br[c*1320 + (2*hh)*40 + w];
      ushort a1 = Br[c*1320 + (2*hh+1)*40 + w];
      uu[hh] = (uint)a0 | ((uint)a1 << 16);
    }
    size_t o = ((size_t)(b*128 + wb*32 + w)*32 + cb*16 + c)*128 + hb*32;
    *(uint4*)(dst + o)      = make_uint4(uu[0],uu[1],uu[2],uu[3]);
    *(uint4*)(dst + o + 8)  = make_uint4(uu[4],uu[5],uu[6],uu[7]);
    *(uint4*)(dst + o + 16) = make_uint4(uu[8],uu[9],uu[10],uu[11]);
    *(uint4*)(dst + o + 24) = make_uint4(uu[12],uu[13],uu[14],uu[15]);
  }
}

// ---------------- fused spatial attention (blocks 0..2047) + channel scores (2048..2559) ----------------
__global__ __launch_bounds__(256) void attn_both(float* __restrict__ ws,
    const float* __restrict__ xu, const float* __restrict__ xd,
    float* __restrict__ out, const float* __restrict__ sch, const float* __restrict__ scw) {
  __shared__ __align__(16) ushort SMEM[36352];   // 72704 B
  __shared__ float m1s[128], l1s[128];
  const int t = threadIdx.x;

  if (blockIdx.x >= 2048) {
    // ===== attn_c1: channel-score accumulation =====
    float* qs = (float*)SMEM;            // [32][260]
    float* ks = qs + 8320;               // [32][260]
    int bid = blockIdx.x - 2048;
    int b = bid >> 6, chunk = bid & 63;
    int n0 = chunk * 256;
    const ushort* qkv16 = (const ushort*)(ws + WS_QKV16);
    const ushort* qp = qkv16 + ((size_t)b*NCO + 64)*NN + n0;
    const ushort* kp = qkv16 + QKV16_D + ((size_t)b*NCO + 64)*NN + n0;
    for (int r = 0; r < 4; r++) {
      int idx = t + r*256;
      int c = idx >> 5, n8 = idx & 31;
      uint4 v = *(const uint4*)(qp + (size_t)c*NN + n8*8);
      uint4 w = *(const uint4*)(kp + (size_t)c*NN + n8*8);
      float* q  = &qs[c*260 + n8*8];
      float* kk = &ks[c*260 + n8*8];
      q[0] = bf2f((ushort)(v.x & 0xffff)); q[1] = bf2f((ushort)(v.x >> 16));
      q[2] = bf2f((ushort)(v.y & 0xffff)); q[3] = bf2f((ushort)(v.y >> 16));
      q[4] = bf2f((ushort)(v.z & 0xffff)); q[5] = bf2f((ushort)(v.z >> 16));
      q[6] = bf2f((ushort)(v.w & 0xffff)); q[7] = bf2f((ushort)(v.w >> 16));
      kk[0] = bf2f((ushort)(w.x & 0xffff)); kk[1] = bf2f((ushort)(w.x >> 16));
      kk[2] = bf2f((ushort)(w.y & 0xffff)); kk[3] = bf2f((ushort)(w.y >> 16));
      kk[4] = bf2f((ushort)(w.z & 0xffff)); kk[5] = bf2f((ushort)(w.z >> 16));
      kk[6] = bf2f((ushort)(w.w & 0xffff)); kk[7] = bf2f((ushort)(w.w >> 16));
    }
    __syncthreads();
    int d = t & 31, cbq = t >> 5;
    float a[4] = {0.f,0.f,0.f,0.f};
    for (int n4 = 0; n4 < 64; n4++) {
      float4 kv = *(const float4*)&ks[d*260 + n4*4];
      #pragma unroll
      for (int r = 0; r < 4; r++) {
        float4 qv = *(const float4*)&qs[(cbq + 8*r)*260 + n4*4];
        a[r] += qv.x*kv.x + qv.y*kv.y + qv.z*kv.z + qv.w*kv.w;
      }
    }
    #pragma unroll
    for (int r = 0; r < 4; r++)
      atomicAdd(&ws[WS_SC + b*1024 + (cbq + 8*r)*32 + d], a[r]);
    return;
  }

  // ===== spatial attention (AXIS 0 = h, 1 = w) =====
  ushort* Qs  = SMEM;            // [128][40]
  ushort* Ks  = SMEM + 5120;     // [128][40]
  ushort* Vds = SMEM + 10240;    // [32][136]
  ushort* Vus = SMEM + 14592;    // [32][136]
  ushort* Pl  = SMEM + 18944;    // [128][136]
  const int AXIS = blockIdx.x >> 10;
  const int rem = blockIdx.x & 1023;
  const int b = rem >> 7, p2 = rem & 127;
  const int wv = t >> 6, lid = t & 63, l15 = lid & 15, l4 = lid >> 4;
  const ushort* slab = (const ushort*)(ws + WS_SLABS);
  const ushort* qsrc  = slab + (AXIS ? OFF_QW : OFF_QH) + (size_t)(b*128 + p2)*4096;
  const ushort* ksrc  = slab + (AXIS ? OFF_KW : OFF_KH) + (size_t)(b*128 + p2)*4096;
  const ushort* vdsrc = slab + (AXIS ? OFF_VWD : OFF_VHD) + (size_t)(b*128 + p2)*4096;
  const ushort* vusrc = slab + (AXIS ? OFF_VWU : OFF_VHU) + (size_t)(b*128 + p2)*4096;
  for (int i = t; i < 2048; i += 256) {
    if (i < 512) {
      int row = i >> 2, q = i & 3;
      *(uint4*)&Qs[row*40 + q*8] = *(const uint4*)(qsrc + row*32 + q*8);
    } else if (i < 1024) {
      int j = i - 512, row = j >> 2, q = j & 3;
      *(uint4*)&Ks[row*40 + q*8] = *(const uint4*)(ksrc + row*32 + q*8);
    } else if (i < 1536) {
      int j = i - 1024, row = j >> 4, ch = j & 15;
      *(uint4*)&Vds[row*136 + ch*8] = *(const uint4*)(vdsrc + row*128 + ch*8);
    } else {
      int j = i - 1536, row = j >> 4, ch = j & 15;
      *(uint4*)&Vus[row*136 + ch*8] = *(const uint4*)(vusrc + row*128 + ch*8);
    }
  }
  const float sc = (AXIS ? scw : sch)[0];
  const int cbas = AXIS ? 32 : 0;
  float ruv0 = ws[WS_RU + b*96 + cbas + l15];
  float ruv1 = ws[WS_RU + b*96 + cbas + 16 + l15];
  float rdv0 = ws[WS_RD + b*96 + cbas + l15];
  float rdv1 = ws[WS_RD + b*96 + cbas + 16 + l15];
  __syncthreads();

  f32x4 z4 = {0.f,0.f,0.f,0.f};
  f32x4 s1[2][8];
  // ---- S1[i][j] = sum_c Q[i][c] K[j][c] ----
  {
    bf16x8 bfr[8];
    #pragma unroll
    for (int tj = 0; tj < 8; tj++) bfr[tj] = ldfrag(&Ks[(tj*16 + l15)*40 + l4*8]);
    #pragma unroll
    for (int ti = 0; ti < 2; ti++) {
      bf16x8 a = ldfrag(&Qs[((2*wv+ti)*16 + l15)*40 + l4*8]);
      #pragma unroll
      for (int tj = 0; tj < 8; tj++)
        s1[ti][tj] = __builtin_amdgcn_mfma_f32_16x16x32_bf16(a, bfr[tj], z4, 0, 0, 0);
    }
  }
  // ---- row softmax over j; write P1 bf16 ----
  #pragma unroll
  for (int ti = 0; ti < 2; ti++) {
    #pragma unroll
    for (int r = 0; r < 4; r++) {
      float mx = -3.0e38f;
      #pragma unroll
      for (int tj = 0; tj < 8; tj++) { float v = s1[ti][tj][r]*sc; s1[ti][tj][r] = v; mx = fmaxf(mx, v); }
      mx = fmaxf(mx, __shfl_xor(mx, 1)); mx = fmaxf(mx, __shfl_xor(mx, 2));
      mx = fmaxf(mx, __shfl_xor(mx, 4)); mx = fmaxf(mx, __shfl_xor(mx, 8));
      float sm = 0.f;
      #pragma unroll
      for (int tj = 0; tj < 8; tj++) { float e = __expf(s1[ti][tj][r] - mx); s1[ti][tj][r] = e; sm += e; }
      sm += __shfl_xor(sm, 1); sm += __shfl_xor(sm, 2); sm += __shfl_xor(sm, 4); sm += __shfl_xor(sm, 8);
      int row = 32*wv + ti*16 + l4*4 + r;
      if (l15 == 0) { m1s[row] = mx; l1s[row] = sm; }
      float inv = __fdividef(1.f, sm);
      #pragma unroll
      for (int tj = 0; tj < 8; tj++) Pl[row*136 + tj*16 + l15] = f2bf(s1[ti][tj][r]*inv);
    }
  }
  __syncthreads();
  // ---- PV1 ----
  f32x4 o1[2][2] = {{z4,z4},{z4,z4}};
  #pragma unroll
  for (int ks = 0; ks < 4; ks++) {
    bf16x8 bv0 = ldfrag(&Vds[l15*136 + ks*32 + l4*8]);
    bf16x8 bv1 = ldfrag(&Vds[(16 + l15)*136 + ks*32 + l4*8]);
    #pragma unroll
    for (int mt = 0; mt < 2; mt++) {
      bf16x8 a = ldfrag(&Pl[((2*wv+mt)*16 + l15)*136 + ks*32 + l4*8]);
      o1[mt][0] = __builtin_amdgcn_mfma_f32_16x16x32_bf16(a, bv0, o1[mt][0], 0, 0, 0);
      o1[mt][1] = __builtin_amdgcn_mfma_f32_16x16x32_bf16(a, bv1, o1[mt][1], 0, 0, 0);
    }
  }
  // ---- S2 = S1^T via mfma(K, Q) ----
  {
    bf16x8 bq[8];
    #pragma unroll
    for (int it = 0; it < 8; it++) bq[it] = ldfrag(&Qs[(it*16 + l15)*40 + l4*8]);
    #pragma unroll
    for (int tjt = 0; tjt < 2; tjt++) {
      bf16x8 a = ldfrag(&Ks[((2*wv+tjt)*16 + l15)*40 + l4*8]);
      #pragma unroll
      for (int it = 0; it < 8; it++)
        s1[tjt][it] = __builtin_amdgcn_mfma_f32_16x16x32_bf16(a, bq[it], z4, 0, 0, 0);
    }
  }
  // ---- pass-2 softmax ----
  if (AXIS == 1) {
    #pragma unroll
    for (int tjt = 0; tjt < 2; tjt++) {
      #pragma unroll
      for (int r = 0; r < 4; r++) {
        float mx = -3.0e38f;
        #pragma unroll
        for (int it = 0; it < 8; it++) { float v = s1[tjt][it][r]*sc; s1[tjt][it][r] = v; mx = fmaxf(mx, v); }
        mx = fmaxf(mx, __shfl_xor(mx, 1)); mx = fmaxf(mx, __shfl_xor(mx, 2));
        mx = fmaxf(mx, __shfl_xor(mx, 4)); mx = fmaxf(mx, __shfl_xor(mx, 8));
        float sm = 0.f;
        #pragma unroll
        for (int it = 0; it < 8; it++) { float e = __expf(s1[tjt][it][r] - mx); s1[tjt][it][r] = e; sm += e; }
        sm += __shfl_xor(sm, 1); sm += __shfl_xor(sm, 2); sm += __shfl_xor(sm, 4); sm += __shfl_xor(sm, 8);
        float inv = __fdividef(1.f, sm);
        #pragma unroll
        for (int it = 0; it < 8; it++) s1[tjt][it][r] *= inv;
      }
    }
  } else {
    float mi[8], li[8];
    #pragma unroll
    for (int it = 0; it < 8; it++) {
      mi[it] = m1s[it*16 + l15];
      li[it] = __fdividef(1.f, l1s[it*16 + l15]);
    }
    #pragma unroll
    for (int tjt = 0; tjt < 2; tjt++)
      #pragma unroll
      for (int it = 0; it < 8; it++)
        #pragma unroll
        for (int r = 0; r < 4; r++)
          s1[tjt][it][r] = __expf(s1[tjt][it][r]*sc - mi[it]) * li[it];
  }
  __syncthreads();
  #pragma unroll
  for (int tjt = 0; tjt < 2; tjt++)
    #pragma unroll
    for (int r = 0; r < 4; r++) {
      int row = 32*wv + tjt*16 + l4*4 + r;
      #pragma unroll
      for (int it = 0; it < 8; it++) Pl[row*136 + it*16 + l15] = f2bf(s1[tjt][it][r]);
    }
  __syncthreads();
  // ---- PV2 ----
  f32x4 o2[2][2] = {{z4,z4},{z4,z4}};
  #pragma unroll
  for (int ks = 0; ks < 4; ks++) {
    bf16x8 bv0 = ldfrag(&Vus[l15*136 + ks*32 + l4*8]);
    bf16x8 bv1 = ldfrag(&Vus[(16 + l15)*136 + ks*32 + l4*8]);
    #pragma unroll
    for (int mt = 0; mt < 2; mt++) {
      bf16x8 a = ldfrag(&Pl[((2*wv+mt)*16 + l15)*136 + ks*32 + l4*8]);
      o2[mt][0] = __builtin_amdgcn_mfma_f32_16x16x32_bf16(a, bv0, o2[mt][0], 0, 0, 0);
      o2[mt][1] = __builtin_amdgcn_mfma_f32_16x16x32_bf16(a, bv1, o2[mt][1], 0, 0, 0);
    }
  }
  __syncthreads();   // reuse Pl as fp32 stage [32][132]
  float* St = (float*)Pl;
  #pragma unroll
  for (int mt = 0; mt < 2; mt++)
    #pragma unroll
    for (int nt = 0; nt < 2; nt++) {
      float ru = nt ? ruv1 : ruv0;
      float rd = nt ? rdv1 : rdv0;
      float4 vv;
      vv.x = o1[mt][nt][0]*ru + o2[mt][nt][0]*rd;
      vv.y = o1[mt][nt][1]*ru + o2[mt][nt][1]*rd;
      vv.z = o1[mt][nt][2]*ru + o2[mt][nt][2]*rd;
      vv.w = o1[mt][nt][3]*ru + o2[mt][nt][3]*rd;
      *(float4*)&St[(nt*16 + l15)*132 + (2*wv+mt)*16 + l4*4] = vv;
    }
  __syncthreads();
  if (AXIS == 1) {
    for (int k = 0; k < 4; k++) {
      int idx = t + k*256;
      int c = idx >> 5, p4 = idx & 31;
      float4 v = *(const float4*)&St[c*132 + p4*4];
      float ca = ws[WS_CADD + b*96 + 32 + c];
      size_t off = ((size_t)(b*NC + 32 + c)*NH + p2)*NWID + p4*4;
      float4 a = *(const float4*)(xu + off);
      float4 dd = *(const float4*)(xd + off);
      v.x += ca + a.x + dd.x; v.y += ca + a.y + dd.y;
      v.z += ca + a.z + dd.z; v.w += ca + a.w + dd.w;
      *(float4*)(out + off) = v;
    }
  } else {
    ushort* oh16 = (ushort*)(ws + WS_OH);
    for (int k = 0; k < 2; k++) {
      int idx = t + k*256;               // 512 = 32c * 16 p8
      int c = idx >> 4, p8 = idx & 15;
      const float* src = &St[c*132 + p8*8];
      uint4 pk;
      pk.x = (uint)f2bf(src[0]) | ((uint)f2bf(src[1]) << 16);
      pk.y = (uint)f2bf(src[2]) | ((uint)f2bf(src[3]) << 16);
      pk.z = (uint)f2bf(src[4]) | ((uint)f2bf(src[5]) << 16);
      pk.w = (uint)f2bf(src[6]) | ((uint)f2bf(src[7]) << 16);
      *(uint4*)(oh16 + ((size_t)(b*128 + p2)*32 + c)*128 + p8*8) = pk;
    }
  }
}

// ---------------- merge h-attn staging into final out (ch 0..31) ----------------
__global__ __launch_bounds__(256) void merge_h(float* __restrict__ ws,
    const float* __restrict__ xu, const float* __restrict__ xd,
    float* __restrict__ out) {
  __shared__ float T[32][33];
  int bid = blockIdx.x;                 // 8b*32c*4ht*4wt = 4096
  int b = bid >> 9, c = (bid >> 4) & 31, ht = (bid >> 2) & 3, wt = bid & 3;
  int t = threadIdx.x;
  const ushort* oh16 = (const ushort*)(ws + WS_OH);
  {
    int w = t >> 3, hq = t & 7;
    uint2 v = *(const uint2*)(oh16 + ((size_t)(b*128 + wt*32 + w)*32 + c)*128 + ht*32 + hq*4);
    T[w][hq*4+0] = bf2f((ushort)(v.x & 0xffff));
    T[w][hq*4+1] = bf2f((ushort)(v.x >> 16));
    T[w][hq*4+2] = bf2f((ushort)(v.y & 0xffff));
    T[w][hq*4+3] = bf2f((ushort)(v.y >> 16));
  }
  __syncthreads();
  {
    int h = t >> 3, w4 = t & 7;
    float ca = ws[WS_CADD + b*96 + c];
    size_t off = ((size_t)(b*NC + c)*NH + ht*32 + h)*NWID + wt*32 + w4*4;
    float4 a = *(const float4*)(xu + off);
    float4 d = *(const float4*)(xd + off);
    float4 v;
    v.x = T[w4*4+0][h] + ca + a.x + d.x;
    v.y = T[w4*4+1][h] + ca + a.y + d.y;
    v.z = T[w4*4+2][h] + ca + a.z + d.z;
    v.w = T[w4*4+3][h] + ca + a.w + d.w;
    *(float4*)(out + off) = v;
  }
}

// ---------------- channel attention: softmax ----------------
__global__ void attn_c2(float* __restrict__ ws, const float* __restrict__ scale_p) {
  int b = blockIdx.x, c = threadIdx.x;
  if (c >= 32) return;
  float sc = scale_p[0];
  float row[32];
  float m = -3.0e38f;
  for (int d = 0; d < 32; d++) { row[d] = ws[WS_SC + b*1024 + c*32 + d] * sc; m = fmaxf(m, row[d]); }
  float s = 0.f;
  for (int d = 0; d < 32; d++) { row[d] = __expf(row[d] - m); s += row[d]; }
  float inv = 1.f / s;
  for (int d = 0; d < 32; d++) ws[WS_AC + b*1024 + c*32 + d] = row[d]*inv;
}

// ---------------- channel attention: apply + epilogue (ch 64..95) ----------------
__global__ __launch_bounds__(256) void attn_c3(float* __restrict__ ws,
    const float* __restrict__ xu, const float* __restrict__ xd,
    float* __restrict__ out) {
  __shared__ float AsT[32][36];
  __shared__ float ruL[32], rdL[32], caL[32];
  int b = blockIdx.x >> 6, chunk = blockIdx.x & 63;
  int t = threadIdx.x;
  for (int r = 0; r < 4; r++) {
    int idx = t + r*256;
    int c = idx >> 5, d = idx & 31;
    AsT[d][c] = ws[WS_AC + b*1024 + idx];
  }
  if (t < 32) {
    ruL[t] = ws[WS_RU + b*96 + 64 + t];
    rdL[t] = ws[WS_RD + b*96 + 64 + t];
    caL[t] = ws[WS_CADD + b*96 + 64 + t];
  }
  __syncthreads();
  int n = chunk*256 + t;
  const ushort* qkv16 = (const ushort*)(ws + WS_QKV16);
  const ushort* vdp = qkv16 + QKV16_D + ((size_t)b*NCO + 160)*NN + n;
  const ushort* vup = qkv16 + ((size_t)b*NCO + 160)*NN + n;
  float acc1[32], acc2[32];
  #pragma unroll
  for (int c2 = 0; c2 < 32; c2++) { acc1[c2]=0.f; acc2[c2]=0.f; }
  for (int d = 0; d < 32; d++) {
    float vd = bf2f(vdp[(size_t)d*NN]);
    float vu = bf2f(vup[(size_t)d*NN]);
    #pragma unroll
    for (int c4 = 0; c4 < 8; c4++) {
      float4 av = *(const float4*)&AsT[d][c4*4];
      acc1[c4*4+0] += av.x*vd; acc2[c4*4+0] += av.x*vu;
      acc1[c4*4+1] += av.y*vd; acc2[c4*4+1] += av.y*vu;
      acc1[c4*4+2] += av.z*vd; acc2[c4*4+2] += av.z*vu;
      acc1[c4*4+3] += av.w*vd; acc2[c4*4+3] += av.w*vu;
    }
  }
  size_t base = ((size_t)(b*NC) + 64)*NN + n;
  #pragma unroll
  for (int c2 = 0; c2 < 32; c2++) {
    size_t off = base + (size_t)c2*NN;
    out[off] = acc1[c2]*ruL[c2] + acc2[c2]*rdL[c2] + caL[c2] + xu[off] + xd[off];
  }
}

extern "C" void kernel_launch(void* const* d_in, const int* in_sizes, int n_in,
                              void* d_out, int out_size, void* d_ws, size_t ws_size,
                              hipStream_t stream) {
  (void)in_sizes; (void)n_in; (void)out_size; (void)ws_size;
  const float* xu   = (const float*)d_in[0];
  const float* xd   = (const float*)d_in[1];
  const float* nwu  = (const float*)d_in[2];
  const float* nbu  = (const float*)d_in[3];
  const float* m1wu = (const float*)d_in[4];
  const float* m1bu = (const float*)d_in[5];
  const float* m2wu = (const float*)d_in[6];
  const float* m2bu = (const float*)d_in[7];
  const float* nwd  = (const float*)d_in[8];
  const float* nbd  = (const float*)d_in[9];
  const float* m1wd = (const float*)d_in[10];
  const float* m1bd = (const float*)d_in[11];
  const float* m2wd = (const float*)d_in[12];
  const float* m2bd = (const float*)d_in[13];
  const float* Wqu  = (const float*)d_in[14];
  const float* bqu  = (const float*)d_in[15];
  const float* Wqd  = (const float*)d_in[16];
  const float* bqd  = (const float*)d_in[17];
  const float* sch  = (const float*)d_in[18];
  const float* scw  = (const float*)d_in[19];
  const float* scc  = (const float*)d_in[20];
  float* ws  = (float*)d_ws;
  float* out = (float*)d_out;

  hipMemsetAsync(d_ws, 0, 8224*sizeof(float), stream);
  reduce_stats<<<1024, 256, 0, stream>>>(xu, xd, ws);
  compute_params<<<1, 256, 0, stream>>>(ws, nwu, nbu, m1wu, m1bu, m2wu, m2bu,
                                        nwd, nbd, m1wd, m1bd, m2wd, m2bd,
                                        Wqu, bqu, Wqd, bqd);
  qkv_gemm<<<4096, 256, 0, stream>>>(ws, xu, xd, Wqu, Wqd);
  qkv_prep<<<512, 256, 0, stream>>>(ws);
  attn_both<<<2560, 256, 0, stream>>>(ws, xu, xd, out, sch, scw);
  merge_h<<<4096, 256, 0, stream>>>(ws, xu, xd, out);
  attn_c2<<<8, 64, 0, stream>>>(ws, scc);
  attn_c3<<<512, 256, 0, stream>>>(ws, xu, xd, out);
}

// Round 12
// 237.759 us; speedup vs baseline: 1.0888x; 1.0888x over previous
//
#include <hip/hip_runtime.h>
#include <math.h>

#define NB 8
#define NC 96
#define NH 128
#define NWID 128
#define NN (NH*NWID)      // 16384
#define NCO 192
#define NM (NC*NN)        // 1572864

// ---------------- workspace layout (float offsets) ----------------
#define WS_SUMS   0                     // [2][8][2]  (zeroed)
#define WS_SC     32                    // [8][32][32] (zeroed)
#define WS_AC     8224                  // [8][32][32]
#define WS_SU     16416                 // [8][96]
#define WS_TU     17184
#define WS_SD     17952
#define WS_TD     18720
#define WS_RU     19488                 // resc_u [8][96]
#define WS_RD     20256                 // resc_d
#define WS_CADD   21024                 // rebias_u+rebias_d
#define WS_BPU    21792                 // eff bias [8][192]
#define WS_BPD    23328
#define WS_WB16   24864                 // bf16 W' [2][8][192][104] (ushort region, 319488 u16)
#define WS_QKV16  327680                // ushort region: 2 tensors x 25165824 u16 (bf16 qkv; only ch 64..127,160..191 valid)
#define QKV16_D   25165824ull
#define WS_SLABS  25493504              // ushort region base: mfma-ready slabs (PACKED rows)
#define SLAB_SZ   4194304ull            // 8*128*128*32 u16 each
#define OFF_QH    (0*SLAB_SZ)           // [8][128w][128h][32c]
#define OFF_KH    (1*SLAB_SZ)
#define OFF_QW    (2*SLAB_SZ)           // [8][128h][128w][32c]
#define OFF_KW    (3*SLAB_SZ)
#define OFF_VHU   (4*SLAB_SZ)           // [8][128w][32c][128h]
#define OFF_VHD   (5*SLAB_SZ)
#define OFF_VWU   (6*SLAB_SZ)           // [8][128h][32c][128w]
#define OFF_VWD   (7*SLAB_SZ)
#define WS_OH     44892160              // bf16 [8][128w][32c][128h] h-attn staging (ushort region)

typedef __attribute__((ext_vector_type(8))) short bf16x8;
typedef __attribute__((ext_vector_type(4))) float f32x4;

static __device__ __forceinline__ float bf2f(ushort u){ return __uint_as_float(((uint)u) << 16); }
static __device__ __forceinline__ ushort f2bf(float f){
  uint b = __float_as_uint(f);
  return (ushort)((b + 0x7fffu + ((b >> 16) & 1u)) >> 16);
}
static __device__ __forceinline__ bf16x8 ldfrag(const ushort* p){
  union { uint4 u; bf16x8 b; } cv; cv.u = *(const uint4*)p; return cv.b;
}

// ---------------- stats reduction: per-sample sum & sumsq ----------------
__global__ __launch_bounds__(256) void reduce_stats(const float* __restrict__ xu,
                                                    const float* __restrict__ xd,
                                                    float* __restrict__ ws) {
  int blk = blockIdx.x;                // 2*8*64
  int tensor = blk >> 9;
  int b = (blk >> 6) & 7;
  int chunk = blk & 63;
  const float* x = tensor ? xd : xu;
  const float4* p = (const float4*)(x + (size_t)b*NM + (size_t)chunk*(NM/64));
  float s = 0.f, sq = 0.f;
  for (int r = 0; r < 24; r++) {
    float4 v = p[threadIdx.x + r*256];
    s  += v.x + v.y + v.z + v.w;
    sq += v.x*v.x + v.y*v.y + v.z*v.z + v.w*v.w;
  }
  for (int o = 32; o; o >>= 1) { s += __shfl_down(s, o); sq += __shfl_down(sq, o); }
  __shared__ float ls[8];
  int wv = threadIdx.x >> 6, ln = threadIdx.x & 63;
  if (ln == 0) { ls[wv*2] = s; ls[wv*2+1] = sq; }
  __syncthreads();
  if (threadIdx.x == 0) {
    s  = ls[0] + ls[2] + ls[4] + ls[6];
    sq = ls[1] + ls[3] + ls[5] + ls[7];
    atomicAdd(&ws[WS_SUMS + (tensor*8 + b)*2],     s);
    atomicAdd(&ws[WS_SUMS + (tensor*8 + b)*2 + 1], sq);
  }
}

// ---------------- derived params ----------------
__global__ void compute_params(float* __restrict__ ws,
    const float* __restrict__ nwu, const float* __restrict__ nbu,
    const float* __restrict__ m1wu, const float* __restrict__ m1bu,
    const float* __restrict__ m2wu, const float* __restrict__ m2bu,
    const float* __restrict__ nwd, const float* __restrict__ nbd,
    const float* __restrict__ m1wd, const float* __restrict__ m1bd,
    const float* __restrict__ m2wd, const float* __restrict__ m2bd,
    const float* __restrict__ Wqu, const float* __restrict__ bqu,
    const float* __restrict__ Wqd, const float* __restrict__ bqd) {
  __shared__ float meanL[16], stdL[16];
  __shared__ float tuL[768], tdL[768];
  int t = threadIdx.x;
  if (t < 16) {
    float s = ws[WS_SUMS + t*2], sq = ws[WS_SUMS + t*2 + 1];
    const float inv = 1.f / (float)NM;
    float mean = s * inv;
    float var  = sq * inv - mean*mean;
    meanL[t] = mean;
    stdL[t]  = sqrtf(var + 1e-5f);
  }
  __syncthreads();
  for (int idx = t; idx < 768; idx += 256) {
    int b = idx / 96, c = idx % 96;
    float mu = meanL[b],   su = stdL[b];
    float md = meanL[8+b], sd = stdL[8+b];
    float scu = nwu[c] / su;
    float scd = nwd[c] / sd;
    float tcu = nbu[c] - mu*scu;
    float tcd = nbd[c] - md*scd;
    tuL[idx] = tcu; tdL[idx] = tcd;
    ws[WS_SU+idx] = scu; ws[WS_TU+idx] = tcu;
    ws[WS_SD+idx] = scd; ws[WS_TD+idx] = tcd;
    ws[WS_RU+idx] = su*m1wu[c] + m1bu[c];
    ws[WS_RD+idx] = sd*m1wd[c] + m1bd[c];
    ws[WS_CADD+idx] = (mu*m2wu[c] + m2bu[c]) + (md*m2wd[c] + m2bd[c]);
  }
  __syncthreads();
  for (int idx = t; idx < 3072; idx += 256) {
    int tensor = idx / 1536;
    int r = idx % 1536;
    int b = r / 192, o = r % 192;
    const float* Wq = tensor ? Wqd : Wqu;
    const float* tt = tensor ? tdL : tuL;
    float acc = tensor ? bqd[o] : bqu[o];
    for (int i = 0; i < 96; i++) acc += Wq[o*96 + i] * tt[b*96 + i];
    ws[(tensor ? WS_BPD : WS_BPU) + r] = acc;
  }
}

// ---------------- W' bf16 [tensor][b][192][104] (A-operand-ready) ----------------
__global__ __launch_bounds__(256) void compute_wprime(float* __restrict__ ws,
    const float* __restrict__ Wqu, const float* __restrict__ Wqd) {
  int idx = blockIdx.x*256 + threadIdx.x;   // 319488 total
  if (idx >= 319488) return;
  int tensor = idx / 159744;
  int r = idx % 159744;
  int b  = r / 19968;
  int r2 = r % 19968;
  int o  = r2 / 104, i = r2 % 104;
  ushort* wb = (ushort*)(ws + WS_WB16);
  ushort v = 0;
  if (i < 96) {
    const float* Wq = tensor ? Wqd : Wqu;
    const float* s  = ws + (tensor ? WS_SD : WS_SU);
    v = f2bf(Wq[o*96 + i] * s[b*96 + i]);
  }
  wb[idx] = v;
}

// ---------------- qkv GEMM via MFMA + fused slab epilogue ----------------
// 64-wide n-tiles; A from precomputed WB16 (linear copy). LDS 33280 B -> 4 blocks/CU.
__global__ __launch_bounds__(256) void qkv_gemm(float* __restrict__ ws,
    const float* __restrict__ xu, const float* __restrict__ xd) {
  __shared__ __align__(16) ushort QL[16640];   // 33280 B
  ushort* Bl = QL;                 // [64][104] u16 = 6656
  ushort* Ah = QL + 6656;          // [96][104] u16 = 9984
  int blk = blockIdx.x;                 // 2 tensor * 8 b * 128 h * 2 wh
  int tensor = blk >> 11;
  int rem = blk & 2047;
  int b = rem >> 8;
  int r2 = rem & 255;
  int nt = r2 >> 1;                     // h
  int wh = r2 & 1;                      // 64-col half
  int n0 = nt*128 + wh*64;
  const float* x = (tensor ? xd : xu) + (size_t)b*NM;
  const ushort* wb = (const ushort*)(ws + WS_WB16) + (size_t)(tensor*8 + b)*19968;
  const float* bp = ws + (tensor ? WS_BPD : WS_BPU) + b*192;
  ushort* outq16 = (ushort*)(ws + WS_QKV16) + (tensor ? QKV16_D : 0) + (size_t)b*NCO*NN;
  ushort* slab = (ushort*)(ws + WS_SLABS);
  const int t = threadIdx.x;
  const int wv = t >> 6, lid = t & 63, l15 = lid & 15, l4 = lid >> 4;

  // stage B: X^T bf16 [64][104]; 768 tasks (i2 0..47, n4 0..15)
  for (int it = 0; it < 3; it++) {
    int idx = t + it*256;
    int i2 = (idx & 7) | ((idx >> 7) << 3);
    int n4 = (idx >> 3) & 15;
    const float* r0 = x + (size_t)(2*i2)*NN + n0 + n4*4;
    float4 a0 = *(const float4*)r0;
    float4 a1 = *(const float4*)(r0 + NN);
    uint p0 = (uint)f2bf(a0.x) | ((uint)f2bf(a1.x) << 16);
    uint p1 = (uint)f2bf(a0.y) | ((uint)f2bf(a1.y) << 16);
    uint p2 = (uint)f2bf(a0.z) | ((uint)f2bf(a1.z) << 16);
    uint p3 = (uint)f2bf(a0.w) | ((uint)f2bf(a1.w) << 16);
    ushort* base = &Bl[(size_t)(n4*4)*104 + 2*i2];
    *(uint*)(base)           = p0;
    *(uint*)(base + 104)     = p1;
    *(uint*)(base + 208)     = p2;
    *(uint*)(base + 312)     = p3;
  }
  // stage A half 0 (W' rows 0..95): 1248 uint4 linear copy
  for (int it = 0; it < 5; it++) {
    int idx = t + it*256;
    if (idx < 1248) ((uint4*)Ah)[idx] = ((const uint4*)wb)[idx];
  }
  __syncthreads();

  // hoist B fragments (wave wv owns cols wv*16..wv*16+15)
  bf16x8 bfr[3];
  #pragma unroll
  for (int s = 0; s < 3; s++)
    bfr[s] = ldfrag(&Bl[(wv*16 + l15)*104 + s*32 + l4*8]);

  f32x4 z4 = {0.f,0.f,0.f,0.f};
  f32x4 acc[12];
  #pragma unroll
  for (int mt = 0; mt < 12; mt++) acc[mt] = z4;
  // half 0: output rows 0..95
  #pragma unroll
  for (int s = 0; s < 3; s++) {
    #pragma unroll
    for (int mt = 0; mt < 6; mt++) {
      bf16x8 a = ldfrag(&Ah[(mt*16 + l15)*104 + s*32 + l4*8]);
      acc[mt] = __builtin_amdgcn_mfma_f32_16x16x32_bf16(a, bfr[s], acc[mt], 0, 0, 0);
    }
  }
  __syncthreads();
  // stage A half 1 (W' rows 96..191)
  for (int it = 0; it < 5; it++) {
    int idx = t + it*256;
    if (idx < 1248) ((uint4*)Ah)[idx] = ((const uint4*)wb)[1248 + idx];
  }
  __syncthreads();
  #pragma unroll
  for (int s = 0; s < 3; s++) {
    #pragma unroll
    for (int mt = 0; mt < 6; mt++) {
      bf16x8 a = ldfrag(&Ah[(mt*16 + l15)*104 + s*32 + l4*8]);
      acc[6+mt] = __builtin_amdgcn_mfma_f32_16x16x32_bf16(a, bfr[s], acc[6+mt], 0, 0, 0);
    }
  }
  __syncthreads();       // all LDS reads done; reuse QL as C bounce [192][72] u16
  ushort* Cl = QL;
  #pragma unroll
  for (int mt = 0; mt < 12; mt++) {
    #pragma unroll
    for (int r = 0; r < 4; r++) {
      int o = mt*16 + l4*4 + r;
      Cl[o*72 + wv*16 + l15] = f2bf(acc[mt][r] + bp[o]);
    }
  }
  __syncthreads();
  // (1) qkv16 store, 96 channels {64..127, 160..191}: 768 uint4
  for (int it = 0; it < 3; it++) {
    int idx = t + it*256;
    int lr = idx >> 3, ch = idx & 7;
    int o = (lr < 64) ? (64 + lr) : (96 + lr);
    *(uint4*)(outq16 + (size_t)o*NN + n0 + ch*8) = *(const uint4*)&Cl[o*72 + ch*8];
  }
  // (2) Q/K h- and w-slabs (PACKED 32c rows): 128 tasks
  if (t < 128) {
    int axis = t >> 6, w = t & 63;
    ushort* dstq = slab + (tensor ? (axis ? OFF_KW : OFF_KH) : (axis ? OFF_QW : OFF_QH));
    size_t o = axis ? ((size_t)(b*128 + nt)*128 + wh*64 + w)*32
                    : ((size_t)(b*128 + wh*64 + w)*128 + nt)*32;
    uint uu[16];
    #pragma unroll
    for (int k = 0; k < 16; k++) {
      ushort a0 = Cl[(axis*32 + 2*k)*72 + w];
      ushort a1 = Cl[(axis*32 + 2*k + 1)*72 + w];
      uu[k] = (uint)a0 | ((uint)a1 << 16);
    }
    *(uint4*)(dstq + o)      = make_uint4(uu[0],uu[1],uu[2],uu[3]);
    *(uint4*)(dstq + o + 8)  = make_uint4(uu[4],uu[5],uu[6],uu[7]);
    *(uint4*)(dstq + o + 16) = make_uint4(uu[8],uu[9],uu[10],uu[11]);
    *(uint4*)(dstq + o + 24) = make_uint4(uu[12],uu[13],uu[14],uu[15]);
  }
  // (3) VW slab (ch 128..159, PACKED 128w rows): 256 uint4 tasks
  {
    ushort* dstv = slab + (tensor ? OFF_VWD : OFF_VWU);
    int c = t >> 3, ch = t & 7;
    *(uint4*)(dstv + ((size_t)(b*128 + nt)*32 + c)*128 + wh*64 + ch*8) =
        *(const uint4*)&Cl[(128 + c)*72 + ch*8];
  }
}

// ---------------- prep: VH slabs only (ch 96..127 -> [b][w][32c][128h] packed) ----------------
__global__ __launch_bounds__(256) void qkv_prep(float* __restrict__ ws) {
  __shared__ __align__(16) ushort Br[16*1320];   // [16c][33h][40w] c-stride 1320
  int bid = blockIdx.x;                           // 2 tensor * 2cb * 8b * 4hb * 4wb = 512
  int tensor = bid >> 8;
  int r = bid & 255;
  int cb = r >> 7, b = (r >> 4) & 7, hb = (r >> 2) & 3, wb = r & 3;
  const ushort* qkv16 = (const ushort*)(ws + WS_QKV16);
  const ushort* src = qkv16 + (tensor ? QKV16_D : 0)
                    + (size_t)b*NCO*NN + (size_t)(96 + cb*16)*NN;
  ushort* dst = (ushort*)(ws + WS_SLABS) + (tensor ? OFF_VHD : OFF_VHU);
  int t = threadIdx.x;
  for (int k = 0; k < 8; k++) {
    int idx = t + k*256;                          // 2048 = 16c*32h*4(w8)
    int c = idx >> 7, h = (idx >> 2) & 31, w8 = idx & 3;
    uint4 v = *(const uint4*)(src + (size_t)c*NN + (size_t)(hb*32 + h)*NWID + wb*32 + w8*8);
    *(uint4*)&Br[c*1320 + h*40 + w8*8] = v;
  }
  __syncthreads();
  for (int k = 0; k < 2; k++) {
    int idx = t + k*256;                          // 512 = 32w*16c
    int w = idx >> 4, c = idx & 15;
    uint uu[16];
    #pragma unroll
    for (int hh = 0; hh < 16; hh++) {
      ushort a0 = Br[c*1320 + (2*hh)*40 + w];
      ushort a1 = Br[c*1320 + (2*hh+1)*40 + w];
      uu[hh] = (uint)a0 | ((uint)a1 << 16);
    }
    size_t o = ((size_t)(b*128 + wb*32 + w)*32 + cb*16 + c)*128 + hb*32;
    *(uint4*)(dst + o)      = make_uint4(uu[0],uu[1],uu[2],uu[3]);
    *(uint4*)(dst + o + 8)  = make_uint4(uu[4],uu[5],uu[6],uu[7]);
    *(uint4*)(dst + o + 16) = make_uint4(uu[8],uu[9],uu[10],uu[11]);
    *(uint4*)(dst + o + 24) = make_uint4(uu[12],uu[13],uu[14],uu[15]);
  }
}

// ---------------- fused spatial attention (blocks 0..2047) + channel scores (2048..2559) ----------------
__global__ __launch_bounds__(256) void attn_both(float* __restrict__ ws,
    const float* __restrict__ xu, const float* __restrict__ xd,
    float* __restrict__ out, const float* __restrict__ sch, const float* __restrict__ scw) {
  __shared__ __align__(16) ushort SMEM[36352];   // 72704 B
  __shared__ float m1s[128], l1s[128];
  const int t = threadIdx.x;

  if (blockIdx.x >= 2048) {
    // ===== attn_c1: channel-score accumulation =====
    float* qs = (float*)SMEM;            // [32][260]
    float* ks = qs + 8320;               // [32][260]
    int bid = blockIdx.x - 2048;
    int b = bid >> 6, chunk = bid & 63;
    int n0 = chunk * 256;
    const ushort* qkv16 = (const ushort*)(ws + WS_QKV16);
    const ushort* qp = qkv16 + ((size_t)b*NCO + 64)*NN + n0;
    const ushort* kp = qkv16 + QKV16_D + ((size_t)b*NCO + 64)*NN + n0;
    for (int r = 0; r < 4; r++) {
      int idx = t + r*256;
      int c = idx >> 5, n8 = idx & 31;
      uint4 v = *(const uint4*)(qp + (size_t)c*NN + n8*8);
      uint4 w = *(const uint4*)(kp + (size_t)c*NN + n8*8);
      float* q  = &qs[c*260 + n8*8];
      float* kk = &ks[c*260 + n8*8];
      q[0] = bf2f((ushort)(v.x & 0xffff)); q[1] = bf2f((ushort)(v.x >> 16));
      q[2] = bf2f((ushort)(v.y & 0xffff)); q[3] = bf2f((ushort)(v.y >> 16));
      q[4] = bf2f((ushort)(v.z & 0xffff)); q[5] = bf2f((ushort)(v.z >> 16));
      q[6] = bf2f((ushort)(v.w & 0xffff)); q[7] = bf2f((ushort)(v.w >> 16));
      kk[0] = bf2f((ushort)(w.x & 0xffff)); kk[1] = bf2f((ushort)(w.x >> 16));
      kk[2] = bf2f((ushort)(w.y & 0xffff)); kk[3] = bf2f((ushort)(w.y >> 16));
      kk[4] = bf2f((ushort)(w.z & 0xffff)); kk[5] = bf2f((ushort)(w.z >> 16));
      kk[6] = bf2f((ushort)(w.w & 0xffff)); kk[7] = bf2f((ushort)(w.w >> 16));
    }
    __syncthreads();
    int d = t & 31, cbq = t >> 5;
    float a[4] = {0.f,0.f,0.f,0.f};
    for (int n4 = 0; n4 < 64; n4++) {
      float4 kv = *(const float4*)&ks[d*260 + n4*4];
      #pragma unroll
      for (int r = 0; r < 4; r++) {
        float4 qv = *(const float4*)&qs[(cbq + 8*r)*260 + n4*4];
        a[r] += qv.x*kv.x + qv.y*kv.y + qv.z*kv.z + qv.w*kv.w;
      }
    }
    #pragma unroll
    for (int r = 0; r < 4; r++)
      atomicAdd(&ws[WS_SC + b*1024 + (cbq + 8*r)*32 + d], a[r]);
    return;
  }

  // ===== spatial attention (AXIS 0 = h, 1 = w) =====
  ushort* Qs  = SMEM;            // [128][40]
  ushort* Ks  = SMEM + 5120;     // [128][40]
  ushort* Vds = SMEM + 10240;    // [32][136]
  ushort* Vus = SMEM + 14592;    // [32][136]
  ushort* Pl  = SMEM + 18944;    // [128][136]
  const int AXIS = blockIdx.x >> 10;
  const int rem = blockIdx.x & 1023;
  const int b = rem >> 7, p2 = rem & 127;
  const int wv = t >> 6, lid = t & 63, l15 = lid & 15, l4 = lid >> 4;
  const ushort* slab = (const ushort*)(ws + WS_SLABS);
  const ushort* qsrc  = slab + (AXIS ? OFF_QW : OFF_QH) + (size_t)(b*128 + p2)*4096;
  const ushort* ksrc  = slab + (AXIS ? OFF_KW : OFF_KH) + (size_t)(b*128 + p2)*4096;
  const ushort* vdsrc = slab + (AXIS ? OFF_VWD : OFF_VHD) + (size_t)(b*128 + p2)*4096;
  const ushort* vusrc = slab + (AXIS ? OFF_VWU : OFF_VHU) + (size_t)(b*128 + p2)*4096;
  for (int i = t; i < 2048; i += 256) {
    if (i < 512) {
      int row = i >> 2, q = i & 3;
      *(uint4*)&Qs[row*40 + q*8] = *(const uint4*)(qsrc + row*32 + q*8);
    } else if (i < 1024) {
      int j = i - 512, row = j >> 2, q = j & 3;
      *(uint4*)&Ks[row*40 + q*8] = *(const uint4*)(ksrc + row*32 + q*8);
    } else if (i < 1536) {
      int j = i - 1024, row = j >> 4, ch = j & 15;
      *(uint4*)&Vds[row*136 + ch*8] = *(const uint4*)(vdsrc + row*128 + ch*8);
    } else {
      int j = i - 1536, row = j >> 4, ch = j & 15;
      *(uint4*)&Vus[row*136 + ch*8] = *(const uint4*)(vusrc + row*128 + ch*8);
    }
  }
  const float sc = (AXIS ? scw : sch)[0];
  const int cbas = AXIS ? 32 : 0;
  float ruv0 = ws[WS_RU + b*96 + cbas + l15];
  float ruv1 = ws[WS_RU + b*96 + cbas + 16 + l15];
  float rdv0 = ws[WS_RD + b*96 + cbas + l15];
  float rdv1 = ws[WS_RD + b*96 + cbas + 16 + l15];
  __syncthreads();

  f32x4 z4 = {0.f,0.f,0.f,0.f};
  f32x4 s1[2][8];
  // ---- S1[i][j] = sum_c Q[i][c] K[j][c] ----
  {
    bf16x8 bfr[8];
    #pragma unroll
    for (int tj = 0; tj < 8; tj++) bfr[tj] = ldfrag(&Ks[(tj*16 + l15)*40 + l4*8]);
    #pragma unroll
    for (int ti = 0; ti < 2; ti++) {
      bf16x8 a = ldfrag(&Qs[((2*wv+ti)*16 + l15)*40 + l4*8]);
      #pragma unroll
      for (int tj = 0; tj < 8; tj++)
        s1[ti][tj] = __builtin_amdgcn_mfma_f32_16x16x32_bf16(a, bfr[tj], z4, 0, 0, 0);
    }
  }
  // ---- row softmax over j; write P1 bf16 ----
  #pragma unroll
  for (int ti = 0; ti < 2; ti++) {
    #pragma unroll
    for (int r = 0; r < 4; r++) {
      float mx = -3.0e38f;
      #pragma unroll
      for (int tj = 0; tj < 8; tj++) { float v = s1[ti][tj][r]*sc; s1[ti][tj][r] = v; mx = fmaxf(mx, v); }
      mx = fmaxf(mx, __shfl_xor(mx, 1)); mx = fmaxf(mx, __shfl_xor(mx, 2));
      mx = fmaxf(mx, __shfl_xor(mx, 4)); mx = fmaxf(mx, __shfl_xor(mx, 8));
      float sm = 0.f;
      #pragma unroll
      for (int tj = 0; tj < 8; tj++) { float e = __expf(s1[ti][tj][r] - mx); s1[ti][tj][r] = e; sm += e; }
      sm += __shfl_xor(sm, 1); sm += __shfl_xor(sm, 2); sm += __shfl_xor(sm, 4); sm += __shfl_xor(sm, 8);
      int row = 32*wv + ti*16 + l4*4 + r;
      if (l15 == 0) { m1s[row] = mx; l1s[row] = sm; }
      float inv = __fdividef(1.f, sm);
      #pragma unroll
      for (int tj = 0; tj < 8; tj++) Pl[row*136 + tj*16 + l15] = f2bf(s1[ti][tj][r]*inv);
    }
  }
  __syncthreads();
  // ---- PV1 ----
  f32x4 o1[2][2] = {{z4,z4},{z4,z4}};
  #pragma unroll
  for (int ks = 0; ks < 4; ks++) {
    bf16x8 bv0 = ldfrag(&Vds[l15*136 + ks*32 + l4*8]);
    bf16x8 bv1 = ldfrag(&Vds[(16 + l15)*136 + ks*32 + l4*8]);
    #pragma unroll
    for (int mt = 0; mt < 2; mt++) {
      bf16x8 a = ldfrag(&Pl[((2*wv+mt)*16 + l15)*136 + ks*32 + l4*8]);
      o1[mt][0] = __builtin_amdgcn_mfma_f32_16x16x32_bf16(a, bv0, o1[mt][0], 0, 0, 0);
      o1[mt][1] = __builtin_amdgcn_mfma_f32_16x16x32_bf16(a, bv1, o1[mt][1], 0, 0, 0);
    }
  }
  // ---- S2 = S1^T via mfma(K, Q) ----
  {
    bf16x8 bq[8];
    #pragma unroll
    for (int it = 0; it < 8; it++) bq[it] = ldfrag(&Qs[(it*16 + l15)*40 + l4*8]);
    #pragma unroll
    for (int tjt = 0; tjt < 2; tjt++) {
      bf16x8 a = ldfrag(&Ks[((2*wv+tjt)*16 + l15)*40 + l4*8]);
      #pragma unroll
      for (int it = 0; it < 8; it++)
        s1[tjt][it] = __builtin_amdgcn_mfma_f32_16x16x32_bf16(a, bq[it], z4, 0, 0, 0);
    }
  }
  // ---- pass-2 softmax ----
  if (AXIS == 1) {
    #pragma unroll
    for (int tjt = 0; tjt < 2; tjt++) {
      #pragma unroll
      for (int r = 0; r < 4; r++) {
        float mx = -3.0e38f;
        #pragma unroll
        for (int it = 0; it < 8; it++) { float v = s1[tjt][it][r]*sc; s1[tjt][it][r] = v; mx = fmaxf(mx, v); }
        mx = fmaxf(mx, __shfl_xor(mx, 1)); mx = fmaxf(mx, __shfl_xor(mx, 2));
        mx = fmaxf(mx, __shfl_xor(mx, 4)); mx = fmaxf(mx, __shfl_xor(mx, 8));
        float sm = 0.f;
        #pragma unroll
        for (int it = 0; it < 8; it++) { float e = __expf(s1[tjt][it][r] - mx); s1[tjt][it][r] = e; sm += e; }
        sm += __shfl_xor(sm, 1); sm += __shfl_xor(sm, 2); sm += __shfl_xor(sm, 4); sm += __shfl_xor(sm, 8);
        float inv = __fdividef(1.f, sm);
        #pragma unroll
        for (int it = 0; it < 8; it++) s1[tjt][it][r] *= inv;
      }
    }
  } else {
    float mi[8], li[8];
    #pragma unroll
    for (int it = 0; it < 8; it++) {
      mi[it] = m1s[it*16 + l15];
      li[it] = __fdividef(1.f, l1s[it*16 + l15]);
    }
    #pragma unroll
    for (int tjt = 0; tjt < 2; tjt++)
      #pragma unroll
      for (int it = 0; it < 8; it++)
        #pragma unroll
        for (int r = 0; r < 4; r++)
          s1[tjt][it][r] = __expf(s1[tjt][it][r]*sc - mi[it]) * li[it];
  }
  __syncthreads();
  #pragma unroll
  for (int tjt = 0; tjt < 2; tjt++)
    #pragma unroll
    for (int r = 0; r < 4; r++) {
      int row = 32*wv + tjt*16 + l4*4 + r;
      #pragma unroll
      for (int it = 0; it < 8; it++) Pl[row*136 + it*16 + l15] = f2bf(s1[tjt][it][r]);
    }
  __syncthreads();
  // ---- PV2 ----
  f32x4 o2[2][2] = {{z4,z4},{z4,z4}};
  #pragma unroll
  for (int ks = 0; ks < 4; ks++) {
    bf16x8 bv0 = ldfrag(&Vus[l15*136 + ks*32 + l4*8]);
    bf16x8 bv1 = ldfrag(&Vus[(16 + l15)*136 + ks*32 + l4*8]);
    #pragma unroll
    for (int mt = 0; mt < 2; mt++) {
      bf16x8 a = ldfrag(&Pl[((2*wv+mt)*16 + l15)*136 + ks*32 + l4*8]);
      o2[mt][0] = __builtin_amdgcn_mfma_f32_16x16x32_bf16(a, bv0, o2[mt][0], 0, 0, 0);
      o2[mt][1] = __builtin_amdgcn_mfma_f32_16x16x32_bf16(a, bv1, o2[mt][1], 0, 0, 0);
    }
  }
  __syncthreads();   // reuse Pl as fp32 stage [32][132]
  float* St = (float*)Pl;
  #pragma unroll
  for (int mt = 0; mt < 2; mt++)
    #pragma unroll
    for (int nt = 0; nt < 2; nt++) {
      float ru = nt ? ruv1 : ruv0;
      float rd = nt ? rdv1 : rdv0;
      float4 vv;
      vv.x = o1[mt][nt][0]*ru + o2[mt][nt][0]*rd;
      vv.y = o1[mt][nt][1]*ru + o2[mt][nt][1]*rd;
      vv.z = o1[mt][nt][2]*ru + o2[mt][nt][2]*rd;
      vv.w = o1[mt][nt][3]*ru + o2[mt][nt][3]*rd;
      *(float4*)&St[(nt*16 + l15)*132 + (2*wv+mt)*16 + l4*4] = vv;
    }
  __syncthreads();
  if (AXIS == 1) {
    for (int k = 0; k < 4; k++) {
      int idx = t + k*256;
      int c = idx >> 5, p4 = idx & 31;
      float4 v = *(const float4*)&St[c*132 + p4*4];
      float ca = ws[WS_CADD + b*96 + 32 + c];
      size_t off = ((size_t)(b*NC + 32 + c)*NH + p2)*NWID + p4*4;
      float4 a = *(const float4*)(xu + off);
      float4 dd = *(const float4*)(xd + off);
      v.x += ca + a.x + dd.x; v.y += ca + a.y + dd.y;
      v.z += ca + a.z + dd.z; v.w += ca + a.w + dd.w;
      *(float4*)(out + off) = v;
    }
  } else {
    ushort* oh16 = (ushort*)(ws + WS_OH);
    for (int k = 0; k < 2; k++) {
      int idx = t + k*256;               // 512 = 32c * 16 p8
      int c = idx >> 4, p8 = idx & 15;
      const float* src = &St[c*132 + p8*8];
      uint4 pk;
      pk.x = (uint)f2bf(src[0]) | ((uint)f2bf(src[1]) << 16);
      pk.y = (uint)f2bf(src[2]) | ((uint)f2bf(src[3]) << 16);
      pk.z = (uint)f2bf(src[4]) | ((uint)f2bf(src[5]) << 16);
      pk.w = (uint)f2bf(src[6]) | ((uint)f2bf(src[7]) << 16);
      *(uint4*)(oh16 + ((size_t)(b*128 + p2)*32 + c)*128 + p8*8) = pk;
    }
  }
}

// ---------------- merge h-attn staging into final out (ch 0..31) ----------------
__global__ __launch_bounds__(256) void merge_h(float* __restrict__ ws,
    const float* __restrict__ xu, const float* __restrict__ xd,
    float* __restrict__ out) {
  __shared__ float T[32][33];
  int bid = blockIdx.x;                 // 8b*32c*4ht*4wt = 4096
  int b = bid >> 9, c = (bid >> 4) & 31, ht = (bid >> 2) & 3, wt = bid & 3;
  int t = threadIdx.x;
  const ushort* oh16 = (const ushort*)(ws + WS_OH);
  {
    int w = t >> 3, hq = t & 7;
    uint2 v = *(const uint2*)(oh16 + ((size_t)(b*128 + wt*32 + w)*32 + c)*128 + ht*32 + hq*4);
    T[w][hq*4+0] = bf2f((ushort)(v.x & 0xffff));
    T[w][hq*4+1] = bf2f((ushort)(v.x >> 16));
    T[w][hq*4+2] = bf2f((ushort)(v.y & 0xffff));
    T[w][hq*4+3] = bf2f((ushort)(v.y >> 16));
  }
  __syncthreads();
  {
    int h = t >> 3, w4 = t & 7;
    float ca = ws[WS_CADD + b*96 + c];
    size_t off = ((size_t)(b*NC + c)*NH + ht*32 + h)*NWID + wt*32 + w4*4;
    float4 a = *(const float4*)(xu + off);
    float4 d = *(const float4*)(xd + off);
    float4 v;
    v.x = T[w4*4+0][h] + ca + a.x + d.x;
    v.y = T[w4*4+1][h] + ca + a.y + d.y;
    v.z = T[w4*4+2][h] + ca + a.z + d.z;
    v.w = T[w4*4+3][h] + ca + a.w + d.w;
    *(float4*)(out + off) = v;
  }
}

// ---------------- channel attention: softmax ----------------
__global__ void attn_c2(float* __restrict__ ws, const float* __restrict__ scale_p) {
  int b = blockIdx.x, c = threadIdx.x;
  if (c >= 32) return;
  float sc = scale_p[0];
  float row[32];
  float m = -3.0e38f;
  for (int d = 0; d < 32; d++) { row[d] = ws[WS_SC + b*1024 + c*32 + d] * sc; m = fmaxf(m, row[d]); }
  float s = 0.f;
  for (int d = 0; d < 32; d++) { row[d] = __expf(row[d] - m); s += row[d]; }
  float inv = 1.f / s;
  for (int d = 0; d < 32; d++) ws[WS_AC + b*1024 + c*32 + d] = row[d]*inv;
}

// ---------------- channel attention: apply + epilogue (ch 64..95) ----------------
__global__ __launch_bounds__(256) void attn_c3(float* __restrict__ ws,
    const float* __restrict__ xu, const float* __restrict__ xd,
    float* __restrict__ out) {
  __shared__ float AsT[32][36];
  __shared__ float ruL[32], rdL[32], caL[32];
  int b = blockIdx.x >> 6, chunk = blockIdx.x & 63;
  int t = threadIdx.x;
  for (int r = 0; r < 4; r++) {
    int idx = t + r*256;
    int c = idx >> 5, d = idx & 31;
    AsT[d][c] = ws[WS_AC + b*1024 + idx];
  }
  if (t < 32) {
    ruL[t] = ws[WS_RU + b*96 + 64 + t];
    rdL[t] = ws[WS_RD + b*96 + 64 + t];
    caL[t] = ws[WS_CADD + b*96 + 64 + t];
  }
  __syncthreads();
  int n = chunk*256 + t;
  const ushort* qkv16 = (const ushort*)(ws + WS_QKV16);
  const ushort* vdp = qkv16 + QKV16_D + ((size_t)b*NCO + 160)*NN + n;
  const ushort* vup = qkv16 + ((size_t)b*NCO + 160)*NN + n;
  float acc1[32], acc2[32];
  #pragma unroll
  for (int c2 = 0; c2 < 32; c2++) { acc1[c2]=0.f; acc2[c2]=0.f; }
  for (int d = 0; d < 32; d++) {
    float vd = bf2f(vdp[(size_t)d*NN]);
    float vu = bf2f(vup[(size_t)d*NN]);
    #pragma unroll
    for (int c4 = 0; c4 < 8; c4++) {
      float4 av = *(const float4*)&AsT[d][c4*4];
      acc1[c4*4+0] += av.x*vd; acc2[c4*4+0] += av.x*vu;
      acc1[c4*4+1] += av.y*vd; acc2[c4*4+1] += av.y*vu;
      acc1[c4*4+2] += av.z*vd; acc2[c4*4+2] += av.z*vu;
      acc1[c4*4+3] += av.w*vd; acc2[c4*4+3] += av.w*vu;
    }
  }
  size_t base = ((size_t)(b*NC) + 64)*NN + n;
  #pragma unroll
  for (int c2 = 0; c2 < 32; c2++) {
    size_t off = base + (size_t)c2*NN;
    out[off] = acc1[c2]*ruL[c2] + acc2[c2]*rdL[c2] + caL[c2] + xu[off] + xd[off];
  }
}

extern "C" void kernel_launch(void* const* d_in, const int* in_sizes, int n_in,
                              void* d_out, int out_size, void* d_ws, size_t ws_size,
                              hipStream_t stream) {
  (void)in_sizes; (void)n_in; (void)out_size; (void)ws_size;
  const float* xu   = (const float*)d_in[0];
  const float* xd   = (const float*)d_in[1];
  const float* nwu  = (const float*)d_in[2];
  const float* nbu  = (const float*)d_in[3];
  const float* m1wu = (const float*)d_in[4];
  const float* m1bu = (const float*)d_in[5];
  const float* m2wu = (const float*)d_in[6];
  const float* m2bu = (const float*)d_in[7];
  const float* nwd  = (const float*)d_in[8];
  const float* nbd  = (const float*)d_in[9];
  const float* m1wd = (const float*)d_in[10];
  const float* m1bd = (const float*)d_in[11];
  const float* m2wd = (const float*)d_in[12];
  const float* m2bd = (const float*)d_in[13];
  const float* Wqu  = (const float*)d_in[14];
  const float* bqu  = (const float*)d_in[15];
  const float* Wqd  = (const float*)d_in[16];
  const float* bqd  = (const float*)d_in[17];
  const float* sch  = (const float*)d_in[18];
  const float* scw  = (const float*)d_in[19];
  const float* scc  = (const float*)d_in[20];
  float* ws  = (float*)d_ws;
  float* out = (float*)d_out;

  hipMemsetAsync(d_ws, 0, 8224*sizeof(float), stream);
  reduce_stats<<<1024, 256, 0, stream>>>(xu, xd, ws);
  compute_params<<<1, 256, 0, stream>>>(ws, nwu, nbu, m1wu, m1bu, m2wu, m2bu,
                                        nwd, nbd, m1wd, m1bd, m2wd, m2bd,
                                        Wqu, bqu, Wqd, bqd);
  compute_wprime<<<1248, 256, 0, stream>>>(ws, Wqu, Wqd);
  qkv_gemm<<<4096, 256, 0, stream>>>(ws, xu, xd);
  qkv_prep<<<512, 256, 0, stream>>>(ws);
  attn_both<<<2560, 256, 0, stream>>>(ws, xu, xd, out, sch, scw);
  merge_h<<<4096, 256, 0, stream>>>(ws, xu, xd, out);
  attn_c2<<<8, 64, 0, stream>>>(ws, scc);
  attn_c3<<<512, 256, 0, stream>>>(ws, xu, xd, out);
}

// Round 13
// 232.112 us; speedup vs baseline: 1.1153x; 1.0243x over previous
//
#include <hip/hip_runtime.h>
#include <math.h>

#define NB 8
#define NC 96
#define NH 128
#define NWID 128
#define NN (NH*NWID)      // 16384
#define NCO 192
#define NM (NC*NN)        // 1572864

// ---------------- workspace layout (float offsets) ----------------
#define WS_SUMS   0                     // [2][8][2]  (zeroed)
#define WS_SC     32                    // [8][32][32] (zeroed)
#define WS_AC     8224                  // (unused)
#define WS_SU     16416                 // [8][96]
#define WS_TU     17184
#define WS_SD     17952
#define WS_TD     18720
#define WS_RU     19488                 // resc_u [8][96]
#define WS_RD     20256                 // resc_d
#define WS_CADD   21024                 // rebias_u+rebias_d
#define WS_BPU    21792                 // eff bias [8][192]
#define WS_BPD    23328
#define WS_WB16   24864                 // bf16 W' [2][8][192][104] (ushort region, 319488 u16)
#define WS_QKV16  327680                // ushort region: 2 tensors x 25165824 u16 (bf16 qkv; only ch 64..127,160..191 valid)
#define QKV16_D   25165824ull
#define WS_SLABS  25493504              // ushort region base: mfma-ready slabs (PACKED rows)
#define SLAB_SZ   4194304ull            // 8*128*128*32 u16 each
#define OFF_QH    (0*SLAB_SZ)           // [8][128w][128h][32c]
#define OFF_KH    (1*SLAB_SZ)
#define OFF_QW    (2*SLAB_SZ)           // [8][128h][128w][32c]
#define OFF_KW    (3*SLAB_SZ)
#define OFF_VHU   (4*SLAB_SZ)           // [8][128w][32c][128h]
#define OFF_VHD   (5*SLAB_SZ)
#define OFF_VWU   (6*SLAB_SZ)           // [8][128h][32c][128w]
#define OFF_VWD   (7*SLAB_SZ)
#define WS_OH     44892160              // bf16 [8][128w][32c][128h] h-attn staging (ushort region)

typedef __attribute__((ext_vector_type(8))) short bf16x8;
typedef __attribute__((ext_vector_type(4))) float f32x4;

static __device__ __forceinline__ float bf2f(ushort u){ return __uint_as_float(((uint)u) << 16); }
static __device__ __forceinline__ ushort f2bf(float f){
  uint b = __float_as_uint(f);
  return (ushort)((b + 0x7fffu + ((b >> 16) & 1u)) >> 16);
}
static __device__ __forceinline__ bf16x8 ldfrag(const ushort* p){
  union { uint4 u; bf16x8 b; } cv; cv.u = *(const uint4*)p; return cv.b;
}

// ---------------- stats reduction: per-sample sum & sumsq ----------------
__global__ __launch_bounds__(256) void reduce_stats(const float* __restrict__ xu,
                                                    const float* __restrict__ xd,
                                                    float* __restrict__ ws) {
  int blk = blockIdx.x;                // 2*8*64
  int tensor = blk >> 9;
  int b = (blk >> 6) & 7;
  int chunk = blk & 63;
  const float* x = tensor ? xd : xu;
  const float4* p = (const float4*)(x + (size_t)b*NM + (size_t)chunk*(NM/64));
  float s = 0.f, sq = 0.f;
  for (int r = 0; r < 24; r++) {
    float4 v = p[threadIdx.x + r*256];
    s  += v.x + v.y + v.z + v.w;
    sq += v.x*v.x + v.y*v.y + v.z*v.z + v.w*v.w;
  }
  for (int o = 32; o; o >>= 1) { s += __shfl_down(s, o); sq += __shfl_down(sq, o); }
  __shared__ float ls[8];
  int wv = threadIdx.x >> 6, ln = threadIdx.x & 63;
  if (ln == 0) { ls[wv*2] = s; ls[wv*2+1] = sq; }
  __syncthreads();
  if (threadIdx.x == 0) {
    s  = ls[0] + ls[2] + ls[4] + ls[6];
    sq = ls[1] + ls[3] + ls[5] + ls[7];
    atomicAdd(&ws[WS_SUMS + (tensor*8 + b)*2],     s);
    atomicAdd(&ws[WS_SUMS + (tensor*8 + b)*2 + 1], sq);
  }
}

// ---------------- derived params ----------------
__global__ void compute_params(float* __restrict__ ws,
    const float* __restrict__ nwu, const float* __restrict__ nbu,
    const float* __restrict__ m1wu, const float* __restrict__ m1bu,
    const float* __restrict__ m2wu, const float* __restrict__ m2bu,
    const float* __restrict__ nwd, const float* __restrict__ nbd,
    const float* __restrict__ m1wd, const float* __restrict__ m1bd,
    const float* __restrict__ m2wd, const float* __restrict__ m2bd,
    const float* __restrict__ Wqu, const float* __restrict__ bqu,
    const float* __restrict__ Wqd, const float* __restrict__ bqd) {
  __shared__ float meanL[16], stdL[16];
  __shared__ float tuL[768], tdL[768];
  int t = threadIdx.x;
  if (t < 16) {
    float s = ws[WS_SUMS + t*2], sq = ws[WS_SUMS + t*2 + 1];
    const float inv = 1.f / (float)NM;
    float mean = s * inv;
    float var  = sq * inv - mean*mean;
    meanL[t] = mean;
    stdL[t]  = sqrtf(var + 1e-5f);
  }
  __syncthreads();
  for (int idx = t; idx < 768; idx += 256) {
    int b = idx / 96, c = idx % 96;
    float mu = meanL[b],   su = stdL[b];
    float md = meanL[8+b], sd = stdL[8+b];
    float scu = nwu[c] / su;
    float scd = nwd[c] / sd;
    float tcu = nbu[c] - mu*scu;
    float tcd = nbd[c] - md*scd;
    tuL[idx] = tcu; tdL[idx] = tcd;
    ws[WS_SU+idx] = scu; ws[WS_TU+idx] = tcu;
    ws[WS_SD+idx] = scd; ws[WS_TD+idx] = tcd;
    ws[WS_RU+idx] = su*m1wu[c] + m1bu[c];
    ws[WS_RD+idx] = sd*m1wd[c] + m1bd[c];
    ws[WS_CADD+idx] = (mu*m2wu[c] + m2bu[c]) + (md*m2wd[c] + m2bd[c]);
  }
  __syncthreads();
  for (int idx = t; idx < 3072; idx += 256) {
    int tensor = idx / 1536;
    int r = idx % 1536;
    int b = r / 192, o = r % 192;
    const float* Wq = tensor ? Wqd : Wqu;
    const float* tt = tensor ? tdL : tuL;
    float acc = tensor ? bqd[o] : bqu[o];
    for (int i = 0; i < 96; i++) acc += Wq[o*96 + i] * tt[b*96 + i];
    ws[(tensor ? WS_BPD : WS_BPU) + r] = acc;
  }
}

// ---------------- W' bf16 [tensor][b][192][104] (A-operand-ready) ----------------
__global__ __launch_bounds__(256) void compute_wprime(float* __restrict__ ws,
    const float* __restrict__ Wqu, const float* __restrict__ Wqd) {
  int idx = blockIdx.x*256 + threadIdx.x;   // 319488 total
  if (idx >= 319488) return;
  int tensor = idx / 159744;
  int r = idx % 159744;
  int b  = r / 19968;
  int r2 = r % 19968;
  int o  = r2 / 104, i = r2 % 104;
  ushort* wb = (ushort*)(ws + WS_WB16);
  ushort v = 0;
  if (i < 96) {
    const float* Wq = tensor ? Wqd : Wqu;
    const float* s  = ws + (tensor ? WS_SD : WS_SU);
    v = f2bf(Wq[o*96 + i] * s[b*96 + i]);
  }
  wb[idx] = v;
}

// ---------------- qkv GEMM via MFMA + fused slab epilogue ----------------
__global__ __launch_bounds__(256) void qkv_gemm(float* __restrict__ ws,
    const float* __restrict__ xu, const float* __restrict__ xd) {
  __shared__ __align__(16) ushort QL[16640];   // 33280 B
  ushort* Bl = QL;                 // [64][104] u16 = 6656
  ushort* Ah = QL + 6656;          // [96][104] u16 = 9984
  int blk = blockIdx.x;                 // 2 tensor * 8 b * 128 h * 2 wh
  int tensor = blk >> 11;
  int rem = blk & 2047;
  int b = rem >> 8;
  int r2 = rem & 255;
  int nt = r2 >> 1;                     // h
  int wh = r2 & 1;                      // 64-col half
  int n0 = nt*128 + wh*64;
  const float* x = (tensor ? xd : xu) + (size_t)b*NM;
  const ushort* wb = (const ushort*)(ws + WS_WB16) + (size_t)(tensor*8 + b)*19968;
  const float* bp = ws + (tensor ? WS_BPD : WS_BPU) + b*192;
  ushort* outq16 = (ushort*)(ws + WS_QKV16) + (tensor ? QKV16_D : 0) + (size_t)b*NCO*NN;
  ushort* slab = (ushort*)(ws + WS_SLABS);
  const int t = threadIdx.x;
  const int wv = t >> 6, lid = t & 63, l15 = lid & 15, l4 = lid >> 4;

  // stage B: X^T bf16 [64][104]; 768 tasks (i2 0..47, n4 0..15)
  for (int it = 0; it < 3; it++) {
    int idx = t + it*256;
    int i2 = (idx & 7) | ((idx >> 7) << 3);
    int n4 = (idx >> 3) & 15;
    const float* r0 = x + (size_t)(2*i2)*NN + n0 + n4*4;
    float4 a0 = *(const float4*)r0;
    float4 a1 = *(const float4*)(r0 + NN);
    uint p0 = (uint)f2bf(a0.x) | ((uint)f2bf(a1.x) << 16);
    uint p1 = (uint)f2bf(a0.y) | ((uint)f2bf(a1.y) << 16);
    uint p2 = (uint)f2bf(a0.z) | ((uint)f2bf(a1.z) << 16);
    uint p3 = (uint)f2bf(a0.w) | ((uint)f2bf(a1.w) << 16);
    ushort* base = &Bl[(size_t)(n4*4)*104 + 2*i2];
    *(uint*)(base)           = p0;
    *(uint*)(base + 104)     = p1;
    *(uint*)(base + 208)     = p2;
    *(uint*)(base + 312)     = p3;
  }
  // stage A half 0 (W' rows 0..95): 1248 uint4 linear copy
  for (int it = 0; it < 5; it++) {
    int idx = t + it*256;
    if (idx < 1248) ((uint4*)Ah)[idx] = ((const uint4*)wb)[idx];
  }
  __syncthreads();

  // hoist B fragments (wave wv owns cols wv*16..wv*16+15)
  bf16x8 bfr[3];
  #pragma unroll
  for (int s = 0; s < 3; s++)
    bfr[s] = ldfrag(&Bl[(wv*16 + l15)*104 + s*32 + l4*8]);

  f32x4 z4 = {0.f,0.f,0.f,0.f};
  f32x4 acc[12];
  #pragma unroll
  for (int mt = 0; mt < 12; mt++) acc[mt] = z4;
  // half 0: output rows 0..95
  #pragma unroll
  for (int s = 0; s < 3; s++) {
    #pragma unroll
    for (int mt = 0; mt < 6; mt++) {
      bf16x8 a = ldfrag(&Ah[(mt*16 + l15)*104 + s*32 + l4*8]);
      acc[mt] = __builtin_amdgcn_mfma_f32_16x16x32_bf16(a, bfr[s], acc[mt], 0, 0, 0);
    }
  }
  __syncthreads();
  // stage A half 1 (W' rows 96..191)
  for (int it = 0; it < 5; it++) {
    int idx = t + it*256;
    if (idx < 1248) ((uint4*)Ah)[idx] = ((const uint4*)wb)[1248 + idx];
  }
  __syncthreads();
  #pragma unroll
  for (int s = 0; s < 3; s++) {
    #pragma unroll
    for (int mt = 0; mt < 6; mt++) {
      bf16x8 a = ldfrag(&Ah[(mt*16 + l15)*104 + s*32 + l4*8]);
      acc[6+mt] = __builtin_amdgcn_mfma_f32_16x16x32_bf16(a, bfr[s], acc[6+mt], 0, 0, 0);
    }
  }
  __syncthreads();       // all LDS reads done; reuse QL as C bounce [192][72] u16
  ushort* Cl = QL;
  #pragma unroll
  for (int mt = 0; mt < 12; mt++) {
    #pragma unroll
    for (int r = 0; r < 4; r++) {
      int o = mt*16 + l4*4 + r;
      Cl[o*72 + wv*16 + l15] = f2bf(acc[mt][r] + bp[o]);
    }
  }
  __syncthreads();
  // (1) qkv16 store, 96 channels {64..127, 160..191}: 768 uint4
  for (int it = 0; it < 3; it++) {
    int idx = t + it*256;
    int lr = idx >> 3, ch = idx & 7;
    int o = (lr < 64) ? (64 + lr) : (96 + lr);
    *(uint4*)(outq16 + (size_t)o*NN + n0 + ch*8) = *(const uint4*)&Cl[o*72 + ch*8];
  }
  // (2) Q/K h- and w-slabs (PACKED 32c rows): 128 tasks
  if (t < 128) {
    int axis = t >> 6, w = t & 63;
    ushort* dstq = slab + (tensor ? (axis ? OFF_KW : OFF_KH) : (axis ? OFF_QW : OFF_QH));
    size_t o = axis ? ((size_t)(b*128 + nt)*128 + wh*64 + w)*32
                    : ((size_t)(b*128 + wh*64 + w)*128 + nt)*32;
    uint uu[16];
    #pragma unroll
    for (int k = 0; k < 16; k++) {
      ushort a0 = Cl[(axis*32 + 2*k)*72 + w];
      ushort a1 = Cl[(axis*32 + 2*k + 1)*72 + w];
      uu[k] = (uint)a0 | ((uint)a1 << 16);
    }
    *(uint4*)(dstq + o)      = make_uint4(uu[0],uu[1],uu[2],uu[3]);
    *(uint4*)(dstq + o + 8)  = make_uint4(uu[4],uu[5],uu[6],uu[7]);
    *(uint4*)(dstq + o + 16) = make_uint4(uu[8],uu[9],uu[10],uu[11]);
    *(uint4*)(dstq + o + 24) = make_uint4(uu[12],uu[13],uu[14],uu[15]);
  }
  // (3) VW slab (ch 128..159, PACKED 128w rows): 256 uint4 tasks
  {
    ushort* dstv = slab + (tensor ? OFF_VWD : OFF_VWU);
    int c = t >> 3, ch = t & 7;
    *(uint4*)(dstv + ((size_t)(b*128 + nt)*32 + c)*128 + wh*64 + ch*8) =
        *(const uint4*)&Cl[(128 + c)*72 + ch*8];
  }
}

// ---------------- prep: VH slabs only (ch 96..127 -> [b][w][32c][128h] packed) ----------------
__global__ __launch_bounds__(256) void qkv_prep(float* __restrict__ ws) {
  __shared__ __align__(16) ushort Br[16*1320];   // [16c][33h][40w] c-stride 1320
  int bid = blockIdx.x;                           // 2 tensor * 2cb * 8b * 4hb * 4wb = 512
  int tensor = bid >> 8;
  int r = bid & 255;
  int cb = r >> 7, b = (r >> 4) & 7, hb = (r >> 2) & 3, wb = r & 3;
  const ushort* qkv16 = (const ushort*)(ws + WS_QKV16);
  const ushort* src = qkv16 + (tensor ? QKV16_D : 0)
                    + (size_t)b*NCO*NN + (size_t)(96 + cb*16)*NN;
  ushort* dst = (ushort*)(ws + WS_SLABS) + (tensor ? OFF_VHD : OFF_VHU);
  int t = threadIdx.x;
  for (int k = 0; k < 8; k++) {
    int idx = t + k*256;                          // 2048 = 16c*32h*4(w8)
    int c = idx >> 7, h = (idx >> 2) & 31, w8 = idx & 3;
    uint4 v = *(const uint4*)(src + (size_t)c*NN + (size_t)(hb*32 + h)*NWID + wb*32 + w8*8);
    *(uint4*)&Br[c*1320 + h*40 + w8*8] = v;
  }
  __syncthreads();
  for (int k = 0; k < 2; k++) {
    int idx = t + k*256;                          // 512 = 32w*16c
    int w = idx >> 4, c = idx & 15;
    uint uu[16];
    #pragma unroll
    for (int hh = 0; hh < 16; hh++) {
      ushort a0 = Br[c*1320 + (2*hh)*40 + w];
      ushort a1 = Br[c*1320 + (2*hh+1)*40 + w];
      uu[hh] = (uint)a0 | ((uint)a1 << 16);
    }
    size_t o = ((size_t)(b*128 + wb*32 + w)*32 + cb*16 + c)*128 + hb*32;
    *(uint4*)(dst + o)      = make_uint4(uu[0],uu[1],uu[2],uu[3]);
    *(uint4*)(dst + o + 8)  = make_uint4(uu[4],uu[5],uu[6],uu[7]);
    *(uint4*)(dst + o + 16) = make_uint4(uu[8],uu[9],uu[10],uu[11]);
    *(uint4*)(dst + o + 24) = make_uint4(uu[12],uu[13],uu[14],uu[15]);
  }
}

// ---------------- fused spatial attention (blocks 0..2047) + channel scores (2048..2559) ----------------
__global__ __launch_bounds__(256) void attn_both(float* __restrict__ ws,
    const float* __restrict__ xu, const float* __restrict__ xd,
    float* __restrict__ out, const float* __restrict__ sch, const float* __restrict__ scw) {
  __shared__ __align__(16) ushort SMEM[36352];   // 72704 B
  __shared__ float m1s[128], l1s[128];
  const int t = threadIdx.x;

  if (blockIdx.x >= 2048) {
    // ===== attn_c1 via MFMA: S[c][d] += sum_n Q[c,n] K[d,n] over 256-col chunk =====
    ushort* qs16 = SMEM;            // [32][264] bf16
    ushort* ks16 = SMEM + 8448;     // [32][264] bf16
    int bid = blockIdx.x - 2048;
    int b = bid >> 6, chunk = bid & 63;
    int n0 = chunk * 256;
    const ushort* qkv16 = (const ushort*)(ws + WS_QKV16);
    const ushort* qp = qkv16 + ((size_t)b*NCO + 64)*NN + n0;
    const ushort* kp = qkv16 + QKV16_D + ((size_t)b*NCO + 64)*NN + n0;
    // stage: 2 matrices x 32 rows x 32 uint4 = 2048 uint4 tasks
    for (int it = 0; it < 8; it++) {
      int idx = t + it*256;
      int mat = idx >> 10;
      int r = idx & 1023;
      int c = r >> 5, n8 = r & 31;
      const ushort* src = (mat ? kp : qp) + (size_t)c*NN + n8*8;
      ushort* dst = (mat ? ks16 : qs16) + c*264 + n8*8;
      *(uint4*)dst = *(const uint4*)src;
    }
    __syncthreads();
    const int wv = t >> 6, lid = t & 63, l15 = lid & 15, l4 = lid >> 4;
    const int cr = wv >> 1, dc = wv & 1;     // wave's 16x16 output tile
    f32x4 z4 = {0.f,0.f,0.f,0.f};
    f32x4 acc = z4;
    #pragma unroll
    for (int ks = 0; ks < 8; ks++) {
      bf16x8 a = ldfrag(&qs16[(cr*16 + l15)*264 + ks*32 + l4*8]);
      bf16x8 bq = ldfrag(&ks16[(dc*16 + l15)*264 + ks*32 + l4*8]);
      acc = __builtin_amdgcn_mfma_f32_16x16x32_bf16(a, bq, acc, 0, 0, 0);
    }
    // C/D map: col = lane&15, row = (lane>>4)*4 + reg
    #pragma unroll
    for (int r = 0; r < 4; r++) {
      int c = cr*16 + l4*4 + r;
      int d = dc*16 + l15;
      atomicAdd(&ws[WS_SC + b*1024 + c*32 + d], acc[r]);
    }
    return;
  }

  // ===== spatial attention (AXIS 0 = h, 1 = w) =====
  ushort* Qs  = SMEM;            // [128][40]
  ushort* Ks  = SMEM + 5120;     // [128][40]
  ushort* Vds = SMEM + 10240;    // [32][136]
  ushort* Vus = SMEM + 14592;    // [32][136]
  ushort* Pl  = SMEM + 18944;    // [128][136]
  const int AXIS = blockIdx.x >> 10;
  const int rem = blockIdx.x & 1023;
  const int b = rem >> 7, p2 = rem & 127;
  const int wv = t >> 6, lid = t & 63, l15 = lid & 15, l4 = lid >> 4;
  const ushort* slab = (const ushort*)(ws + WS_SLABS);
  const ushort* qsrc  = slab + (AXIS ? OFF_QW : OFF_QH) + (size_t)(b*128 + p2)*4096;
  const ushort* ksrc  = slab + (AXIS ? OFF_KW : OFF_KH) + (size_t)(b*128 + p2)*4096;
  const ushort* vdsrc = slab + (AXIS ? OFF_VWD : OFF_VHD) + (size_t)(b*128 + p2)*4096;
  const ushort* vusrc = slab + (AXIS ? OFF_VWU : OFF_VHU) + (size_t)(b*128 + p2)*4096;
  for (int i = t; i < 2048; i += 256) {
    if (i < 512) {
      int row = i >> 2, q = i & 3;
      *(uint4*)&Qs[row*40 + q*8] = *(const uint4*)(qsrc + row*32 + q*8);
    } else if (i < 1024) {
      int j = i - 512, row = j >> 2, q = j & 3;
      *(uint4*)&Ks[row*40 + q*8] = *(const uint4*)(ksrc + row*32 + q*8);
    } else if (i < 1536) {
      int j = i - 1024, row = j >> 4, ch = j & 15;
      *(uint4*)&Vds[row*136 + ch*8] = *(const uint4*)(vdsrc + row*128 + ch*8);
    } else {
      int j = i - 1536, row = j >> 4, ch = j & 15;
      *(uint4*)&Vus[row*136 + ch*8] = *(const uint4*)(vusrc + row*128 + ch*8);
    }
  }
  const float sc = (AXIS ? scw : sch)[0];
  const int cbas = AXIS ? 32 : 0;
  float ruv0 = ws[WS_RU + b*96 + cbas + l15];
  float ruv1 = ws[WS_RU + b*96 + cbas + 16 + l15];
  float rdv0 = ws[WS_RD + b*96 + cbas + l15];
  float rdv1 = ws[WS_RD + b*96 + cbas + 16 + l15];
  __syncthreads();

  f32x4 z4 = {0.f,0.f,0.f,0.f};
  f32x4 s1[2][8];
  // ---- S1[i][j] = sum_c Q[i][c] K[j][c] ----
  {
    bf16x8 bfr[8];
    #pragma unroll
    for (int tj = 0; tj < 8; tj++) bfr[tj] = ldfrag(&Ks[(tj*16 + l15)*40 + l4*8]);
    #pragma unroll
    for (int ti = 0; ti < 2; ti++) {
      bf16x8 a = ldfrag(&Qs[((2*wv+ti)*16 + l15)*40 + l4*8]);
      #pragma unroll
      for (int tj = 0; tj < 8; tj++)
        s1[ti][tj] = __builtin_amdgcn_mfma_f32_16x16x32_bf16(a, bfr[tj], z4, 0, 0, 0);
    }
  }
  // ---- row softmax over j; write P1 bf16 ----
  #pragma unroll
  for (int ti = 0; ti < 2; ti++) {
    #pragma unroll
    for (int r = 0; r < 4; r++) {
      float mx = -3.0e38f;
      #pragma unroll
      for (int tj = 0; tj < 8; tj++) { float v = s1[ti][tj][r]*sc; s1[ti][tj][r] = v; mx = fmaxf(mx, v); }
      mx = fmaxf(mx, __shfl_xor(mx, 1)); mx = fmaxf(mx, __shfl_xor(mx, 2));
      mx = fmaxf(mx, __shfl_xor(mx, 4)); mx = fmaxf(mx, __shfl_xor(mx, 8));
      float sm = 0.f;
      #pragma unroll
      for (int tj = 0; tj < 8; tj++) { float e = __expf(s1[ti][tj][r] - mx); s1[ti][tj][r] = e; sm += e; }
      sm += __shfl_xor(sm, 1); sm += __shfl_xor(sm, 2); sm += __shfl_xor(sm, 4); sm += __shfl_xor(sm, 8);
      int row = 32*wv + ti*16 + l4*4 + r;
      if (l15 == 0) { m1s[row] = mx; l1s[row] = sm; }
      float inv = __fdividef(1.f, sm);
      #pragma unroll
      for (int tj = 0; tj < 8; tj++) Pl[row*136 + tj*16 + l15] = f2bf(s1[ti][tj][r]*inv);
    }
  }
  __syncthreads();
  // ---- PV1 ----
  f32x4 o1[2][2] = {{z4,z4},{z4,z4}};
  #pragma unroll
  for (int ks = 0; ks < 4; ks++) {
    bf16x8 bv0 = ldfrag(&Vds[l15*136 + ks*32 + l4*8]);
    bf16x8 bv1 = ldfrag(&Vds[(16 + l15)*136 + ks*32 + l4*8]);
    #pragma unroll
    for (int mt = 0; mt < 2; mt++) {
      bf16x8 a = ldfrag(&Pl[((2*wv+mt)*16 + l15)*136 + ks*32 + l4*8]);
      o1[mt][0] = __builtin_amdgcn_mfma_f32_16x16x32_bf16(a, bv0, o1[mt][0], 0, 0, 0);
      o1[mt][1] = __builtin_amdgcn_mfma_f32_16x16x32_bf16(a, bv1, o1[mt][1], 0, 0, 0);
    }
  }
  // ---- S2 = S1^T via mfma(K, Q) ----
  {
    bf16x8 bq[8];
    #pragma unroll
    for (int it = 0; it < 8; it++) bq[it] = ldfrag(&Qs[(it*16 + l15)*40 + l4*8]);
    #pragma unroll
    for (int tjt = 0; tjt < 2; tjt++) {
      bf16x8 a = ldfrag(&Ks[((2*wv+tjt)*16 + l15)*40 + l4*8]);
      #pragma unroll
      for (int it = 0; it < 8; it++)
        s1[tjt][it] = __builtin_amdgcn_mfma_f32_16x16x32_bf16(a, bq[it], z4, 0, 0, 0);
    }
  }
  // ---- pass-2 softmax ----
  if (AXIS == 1) {
    #pragma unroll
    for (int tjt = 0; tjt < 2; tjt++) {
      #pragma unroll
      for (int r = 0; r < 4; r++) {
        float mx = -3.0e38f;
        #pragma unroll
        for (int it = 0; it < 8; it++) { float v = s1[tjt][it][r]*sc; s1[tjt][it][r] = v; mx = fmaxf(mx, v); }
        mx = fmaxf(mx, __shfl_xor(mx, 1)); mx = fmaxf(mx, __shfl_xor(mx, 2));
        mx = fmaxf(mx, __shfl_xor(mx, 4)); mx = fmaxf(mx, __shfl_xor(mx, 8));
        float sm = 0.f;
        #pragma unroll
        for (int it = 0; it < 8; it++) { float e = __expf(s1[tjt][it][r] - mx); s1[tjt][it][r] = e; sm += e; }
        sm += __shfl_xor(sm, 1); sm += __shfl_xor(sm, 2); sm += __shfl_xor(sm, 4); sm += __shfl_xor(sm, 8);
        float inv = __fdividef(1.f, sm);
        #pragma unroll
        for (int it = 0; it < 8; it++) s1[tjt][it][r] *= inv;
      }
    }
  } else {
    float mi[8], li[8];
    #pragma unroll
    for (int it = 0; it < 8; it++) {
      mi[it] = m1s[it*16 + l15];
      li[it] = __fdividef(1.f, l1s[it*16 + l15]);
    }
    #pragma unroll
    for (int tjt = 0; tjt < 2; tjt++)
      #pragma unroll
      for (int it = 0; it < 8; it++)
        #pragma unroll
        for (int r = 0; r < 4; r++)
          s1[tjt][it][r] = __expf(s1[tjt][it][r]*sc - mi[it]) * li[it];
  }
  __syncthreads();
  #pragma unroll
  for (int tjt = 0; tjt < 2; tjt++)
    #pragma unroll
    for (int r = 0; r < 4; r++) {
      int row = 32*wv + tjt*16 + l4*4 + r;
      #pragma unroll
      for (int it = 0; it < 8; it++) Pl[row*136 + it*16 + l15] = f2bf(s1[tjt][it][r]);
    }
  __syncthreads();
  // ---- PV2 ----
  f32x4 o2[2][2] = {{z4,z4},{z4,z4}};
  #pragma unroll
  for (int ks = 0; ks < 4; ks++) {
    bf16x8 bv0 = ldfrag(&Vus[l15*136 + ks*32 + l4*8]);
    bf16x8 bv1 = ldfrag(&Vus[(16 + l15)*136 + ks*32 + l4*8]);
    #pragma unroll
    for (int mt = 0; mt < 2; mt++) {
      bf16x8 a = ldfrag(&Pl[((2*wv+mt)*16 + l15)*136 + ks*32 + l4*8]);
      o2[mt][0] = __builtin_amdgcn_mfma_f32_16x16x32_bf16(a, bv0, o2[mt][0], 0, 0, 0);
      o2[mt][1] = __builtin_amdgcn_mfma_f32_16x16x32_bf16(a, bv1, o2[mt][1], 0, 0, 0);
    }
  }
  __syncthreads();   // reuse Pl as fp32 stage [32][132]
  float* St = (float*)Pl;
  #pragma unroll
  for (int mt = 0; mt < 2; mt++)
    #pragma unroll
    for (int nt = 0; nt < 2; nt++) {
      float ru = nt ? ruv1 : ruv0;
      float rd = nt ? rdv1 : rdv0;
      float4 vv;
      vv.x = o1[mt][nt][0]*ru + o2[mt][nt][0]*rd;
      vv.y = o1[mt][nt][1]*ru + o2[mt][nt][1]*rd;
      vv.z = o1[mt][nt][2]*ru + o2[mt][nt][2]*rd;
      vv.w = o1[mt][nt][3]*ru + o2[mt][nt][3]*rd;
      *(float4*)&St[(nt*16 + l15)*132 + (2*wv+mt)*16 + l4*4] = vv;
    }
  __syncthreads();
  if (AXIS == 1) {
    for (int k = 0; k < 4; k++) {
      int idx = t + k*256;
      int c = idx >> 5, p4 = idx & 31;
      float4 v = *(const float4*)&St[c*132 + p4*4];
      float ca = ws[WS_CADD + b*96 + 32 + c];
      size_t off = ((size_t)(b*NC + 32 + c)*NH + p2)*NWID + p4*4;
      float4 a = *(const float4*)(xu + off);
      float4 dd = *(const float4*)(xd + off);
      v.x += ca + a.x + dd.x; v.y += ca + a.y + dd.y;
      v.z += ca + a.z + dd.z; v.w += ca + a.w + dd.w;
      *(float4*)(out + off) = v;
    }
  } else {
    ushort* oh16 = (ushort*)(ws + WS_OH);
    for (int k = 0; k < 2; k++) {
      int idx = t + k*256;               // 512 = 32c * 16 p8
      int c = idx >> 4, p8 = idx & 15;
      const float* src = &St[c*132 + p8*8];
      uint4 pk;
      pk.x = (uint)f2bf(src[0]) | ((uint)f2bf(src[1]) << 16);
      pk.y = (uint)f2bf(src[2]) | ((uint)f2bf(src[3]) << 16);
      pk.z = (uint)f2bf(src[4]) | ((uint)f2bf(src[5]) << 16);
      pk.w = (uint)f2bf(src[6]) | ((uint)f2bf(src[7]) << 16);
      *(uint4*)(oh16 + ((size_t)(b*128 + p2)*32 + c)*128 + p8*8) = pk;
    }
  }
}

// ---------------- merge h-attn staging into final out (ch 0..31) ----------------
__global__ __launch_bounds__(256) void merge_h(float* __restrict__ ws,
    const float* __restrict__ xu, const float* __restrict__ xd,
    float* __restrict__ out) {
  __shared__ float T[32][33];
  int bid = blockIdx.x;                 // 8b*32c*4ht*4wt = 4096
  int b = bid >> 9, c = (bid >> 4) & 31, ht = (bid >> 2) & 3, wt = bid & 3;
  int t = threadIdx.x;
  const ushort* oh16 = (const ushort*)(ws + WS_OH);
  {
    int w = t >> 3, hq = t & 7;
    uint2 v = *(const uint2*)(oh16 + ((size_t)(b*128 + wt*32 + w)*32 + c)*128 + ht*32 + hq*4);
    T[w][hq*4+0] = bf2f((ushort)(v.x & 0xffff));
    T[w][hq*4+1] = bf2f((ushort)(v.x >> 16));
    T[w][hq*4+2] = bf2f((ushort)(v.y & 0xffff));
    T[w][hq*4+3] = bf2f((ushort)(v.y >> 16));
  }
  __syncthreads();
  {
    int h = t >> 3, w4 = t & 7;
    float ca = ws[WS_CADD + b*96 + c];
    size_t off = ((size_t)(b*NC + c)*NH + ht*32 + h)*NWID + wt*32 + w4*4;
    float4 a = *(const float4*)(xu + off);
    float4 d = *(const float4*)(xd + off);
    float4 v;
    v.x = T[w4*4+0][h] + ca + a.x + d.x;
    v.y = T[w4*4+1][h] + ca + a.y + d.y;
    v.z = T[w4*4+2][h] + ca + a.z + d.z;
    v.w = T[w4*4+3][h] + ca + a.w + d.w;
    *(float4*)(out + off) = v;
  }
}

// ---------------- channel attention: softmax (in-block) + apply + epilogue (ch 64..95) ----------------
__global__ __launch_bounds__(256) void attn_c3(float* __restrict__ ws,
    const float* __restrict__ xu, const float* __restrict__ xd,
    float* __restrict__ out, const float* __restrict__ scale_p) {
  __shared__ float scl[32][33];
  __shared__ float AsT[32][36];
  __shared__ float ruL[32], rdL[32], caL[32];
  int b = blockIdx.x >> 6, chunk = blockIdx.x & 63;
  int t = threadIdx.x;
  // load raw scores
  for (int r = 0; r < 4; r++) {
    int idx = t + r*256;
    int c = idx >> 5, d = idx & 31;
    scl[c][d] = ws[WS_SC + b*1024 + idx];
  }
  if (t < 32) {
    ruL[t] = ws[WS_RU + b*96 + 64 + t];
    rdL[t] = ws[WS_RD + b*96 + 64 + t];
    caL[t] = ws[WS_CADD + b*96 + 64 + t];
  }
  __syncthreads();
  // per-row softmax (32 rows, thread t<32 handles row t), write transposed
  if (t < 32) {
    float sc = scale_p[0];
    float row[32];
    float m = -3.0e38f;
    for (int d = 0; d < 32; d++) { row[d] = scl[t][d] * sc; m = fmaxf(m, row[d]); }
    float s = 0.f;
    for (int d = 0; d < 32; d++) { row[d] = __expf(row[d] - m); s += row[d]; }
    float inv = 1.f / s;
    for (int d = 0; d < 32; d++) AsT[d][t] = row[d]*inv;
  }
  __syncthreads();
  int n = chunk*256 + t;
  const ushort* qkv16 = (const ushort*)(ws + WS_QKV16);
  const ushort* vdp = qkv16 + QKV16_D + ((size_t)b*NCO + 160)*NN + n;
  const ushort* vup = qkv16 + ((size_t)b*NCO + 160)*NN + n;
  float acc1[32], acc2[32];
  #pragma unroll
  for (int c2 = 0; c2 < 32; c2++) { acc1[c2]=0.f; acc2[c2]=0.f; }
  for (int d = 0; d < 32; d++) {
    float vd = bf2f(vdp[(size_t)d*NN]);
    float vu = bf2f(vup[(size_t)d*NN]);
    #pragma unroll
    for (int c4 = 0; c4 < 8; c4++) {
      float4 av = *(const float4*)&AsT[d][c4*4];
      acc1[c4*4+0] += av.x*vd; acc2[c4*4+0] += av.x*vu;
      acc1[c4*4+1] += av.y*vd; acc2[c4*4+1] += av.y*vu;
      acc1[c4*4+2] += av.z*vd; acc2[c4*4+2] += av.z*vu;
      acc1[c4*4+3] += av.w*vd; acc2[c4*4+3] += av.w*vu;
    }
  }
  size_t base = ((size_t)(b*NC) + 64)*NN + n;
  #pragma unroll
  for (int c2 = 0; c2 < 32; c2++) {
    size_t off = base + (size_t)c2*NN;
    out[off] = acc1[c2]*ruL[c2] + acc2[c2]*rdL[c2] + caL[c2] + xu[off] + xd[off];
  }
}

extern "C" void kernel_launch(void* const* d_in, const int* in_sizes, int n_in,
                              void* d_out, int out_size, void* d_ws, size_t ws_size,
                              hipStream_t stream) {
  (void)in_sizes; (void)n_in; (void)out_size; (void)ws_size;
  const float* xu   = (const float*)d_in[0];
  const float* xd   = (const float*)d_in[1];
  const float* nwu  = (const float*)d_in[2];
  const float* nbu  = (const float*)d_in[3];
  const float* m1wu = (const float*)d_in[4];
  const float* m1bu = (const float*)d_in[5];
  const float* m2wu = (const float*)d_in[6];
  const float* m2bu = (const float*)d_in[7];
  const float* nwd  = (const float*)d_in[8];
  const float* nbd  = (const float*)d_in[9];
  const float* m1wd = (const float*)d_in[10];
  const float* m1bd = (const float*)d_in[11];
  const float* m2wd = (const float*)d_in[12];
  const float* m2bd = (const float*)d_in[13];
  const float* Wqu  = (const float*)d_in[14];
  const float* bqu  = (const float*)d_in[15];
  const float* Wqd  = (const float*)d_in[16];
  const float* bqd  = (const float*)d_in[17];
  const float* sch  = (const float*)d_in[18];
  const float* scw  = (const float*)d_in[19];
  const float* scc  = (const float*)d_in[20];
  float* ws  = (float*)d_ws;
  float* out = (float*)d_out;

  hipMemsetAsync(d_ws, 0, 8224*sizeof(float), stream);
  reduce_stats<<<1024, 256, 0, stream>>>(xu, xd, ws);
  compute_params<<<1, 256, 0, stream>>>(ws, nwu, nbu, m1wu, m1bu, m2wu, m2bu,
                                        nwd, nbd, m1wd, m1bd, m2wd, m2bd,
                                        Wqu, bqu, Wqd, bqd);
  compute_wprime<<<1248, 256, 0, stream>>>(ws, Wqu, Wqd);
  qkv_gemm<<<4096, 256, 0, stream>>>(ws, xu, xd);
  qkv_prep<<<512, 256, 0, stream>>>(ws);
  attn_both<<<2560, 256, 0, stream>>>(ws, xu, xd, out, sch, scw);
  merge_h<<<4096, 256, 0, stream>>>(ws, xu, xd, out);
  attn_c3<<<512, 256, 0, stream>>>(ws, xu, xd, out, scc);
}

// Round 14
// 229.069 us; speedup vs baseline: 1.1301x; 1.0133x over previous
//
#include <hip/hip_runtime.h>
#include <math.h>

#define NB 8
#define NC 96
#define NH 128
#define NWID 128
#define NN (NH*NWID)      // 16384
#define NCO 192
#define NM (NC*NN)        // 1572864

// ---------------- workspace layout (float offsets) ----------------
#define WS_SUMS   0                     // [2][8][2]  (zeroed)
#define WS_SC     32                    // [8][32][32] (zeroed)
#define WS_SU     16416                 // [8][96]
#define WS_TU     17184
#define WS_SD     17952
#define WS_TD     18720
#define WS_RU     19488                 // resc_u [8][96]
#define WS_RD     20256                 // resc_d
#define WS_CADD   21024                 // rebias_u+rebias_d
#define WS_BPU    21792                 // eff bias [8][192]
#define WS_BPD    23328
#define WS_WB16   24864                 // bf16 W' [2][8][192][104] (ushort region, 319488 u16)
#define WS_QKV16  327680                // ushort region: 2 tensors x 25165824 u16 (bf16 qkv; only ch 64..127,160..191 valid)
#define QKV16_D   25165824ull
#define WS_SLABS  25493504              // ushort region base: mfma-ready slabs (PACKED rows)
#define SLAB_SZ   4194304ull            // 8*128*128*32 u16 each
#define OFF_QH    (0*SLAB_SZ)           // [8][128w][128h][32c]
#define OFF_KH    (1*SLAB_SZ)
#define OFF_QW    (2*SLAB_SZ)           // [8][128h][128w][32c]
#define OFF_KW    (3*SLAB_SZ)
#define OFF_VHU   (4*SLAB_SZ)           // [8][128w][32c][128h]
#define OFF_VHD   (5*SLAB_SZ)
#define OFF_VWU   (6*SLAB_SZ)           // [8][128h][32c][128w]
#define OFF_VWD   (7*SLAB_SZ)
#define WS_OH     44892160              // bf16 [8][128w][32c][128h] h-attn staging (ushort region)

typedef __attribute__((ext_vector_type(8))) short bf16x8;
typedef __attribute__((ext_vector_type(4))) float f32x4;

static __device__ __forceinline__ float bf2f(ushort u){ return __uint_as_float(((uint)u) << 16); }
static __device__ __forceinline__ ushort f2bf(float f){
  uint b = __float_as_uint(f);
  return (ushort)((b + 0x7fffu + ((b >> 16) & 1u)) >> 16);
}
static __device__ __forceinline__ bf16x8 ldfrag(const ushort* p){
  union { uint4 u; bf16x8 b; } cv; cv.u = *(const uint4*)p; return cv.b;
}

// ---------------- stats reduction: per-sample sum & sumsq ----------------
__global__ __launch_bounds__(256) void reduce_stats(const float* __restrict__ xu,
                                                    const float* __restrict__ xd,
                                                    float* __restrict__ ws) {
  int blk = blockIdx.x;                // 2*8*64
  int tensor = blk >> 9;
  int b = (blk >> 6) & 7;
  int chunk = blk & 63;
  const float* x = tensor ? xd : xu;
  const float4* p = (const float4*)(x + (size_t)b*NM + (size_t)chunk*(NM/64));
  float s = 0.f, sq = 0.f;
  for (int r = 0; r < 24; r++) {
    float4 v = p[threadIdx.x + r*256];
    s  += v.x + v.y + v.z + v.w;
    sq += v.x*v.x + v.y*v.y + v.z*v.z + v.w*v.w;
  }
  for (int o = 32; o; o >>= 1) { s += __shfl_down(s, o); sq += __shfl_down(sq, o); }
  __shared__ float ls[8];
  int wv = threadIdx.x >> 6, ln = threadIdx.x & 63;
  if (ln == 0) { ls[wv*2] = s; ls[wv*2+1] = sq; }
  __syncthreads();
  if (threadIdx.x == 0) {
    s  = ls[0] + ls[2] + ls[4] + ls[6];
    sq = ls[1] + ls[3] + ls[5] + ls[7];
    atomicAdd(&ws[WS_SUMS + (tensor*8 + b)*2],     s);
    atomicAdd(&ws[WS_SUMS + (tensor*8 + b)*2 + 1], sq);
  }
}

// ---------------- derived params ----------------
__global__ void compute_params(float* __restrict__ ws,
    const float* __restrict__ nwu, const float* __restrict__ nbu,
    const float* __restrict__ m1wu, const float* __restrict__ m1bu,
    const float* __restrict__ m2wu, const float* __restrict__ m2bu,
    const float* __restrict__ nwd, const float* __restrict__ nbd,
    const float* __restrict__ m1wd, const float* __restrict__ m1bd,
    const float* __restrict__ m2wd, const float* __restrict__ m2bd,
    const float* __restrict__ Wqu, const float* __restrict__ bqu,
    const float* __restrict__ Wqd, const float* __restrict__ bqd) {
  __shared__ float meanL[16], stdL[16];
  __shared__ float tuL[768], tdL[768];
  int t = threadIdx.x;
  if (t < 16) {
    float s = ws[WS_SUMS + t*2], sq = ws[WS_SUMS + t*2 + 1];
    const float inv = 1.f / (float)NM;
    float mean = s * inv;
    float var  = sq * inv - mean*mean;
    meanL[t] = mean;
    stdL[t]  = sqrtf(var + 1e-5f);
  }
  __syncthreads();
  for (int idx = t; idx < 768; idx += 256) {
    int b = idx / 96, c = idx % 96;
    float mu = meanL[b],   su = stdL[b];
    float md = meanL[8+b], sd = stdL[8+b];
    float scu = nwu[c] / su;
    float scd = nwd[c] / sd;
    float tcu = nbu[c] - mu*scu;
    float tcd = nbd[c] - md*scd;
    tuL[idx] = tcu; tdL[idx] = tcd;
    ws[WS_SU+idx] = scu; ws[WS_TU+idx] = tcu;
    ws[WS_SD+idx] = scd; ws[WS_TD+idx] = tcd;
    ws[WS_RU+idx] = su*m1wu[c] + m1bu[c];
    ws[WS_RD+idx] = sd*m1wd[c] + m1bd[c];
    ws[WS_CADD+idx] = (mu*m2wu[c] + m2bu[c]) + (md*m2wd[c] + m2bd[c]);
  }
  __syncthreads();
  for (int idx = t; idx < 3072; idx += 256) {
    int tensor = idx / 1536;
    int r = idx % 1536;
    int b = r / 192, o = r % 192;
    const float* Wq = tensor ? Wqd : Wqu;
    const float* tt = tensor ? tdL : tuL;
    float acc = tensor ? bqd[o] : bqu[o];
    for (int i = 0; i < 96; i++) acc += Wq[o*96 + i] * tt[b*96 + i];
    ws[(tensor ? WS_BPD : WS_BPU) + r] = acc;
  }
}

// ---------------- W' bf16 [tensor][b][192][104] (A-operand-ready) ----------------
__global__ __launch_bounds__(256) void compute_wprime(float* __restrict__ ws,
    const float* __restrict__ Wqu, const float* __restrict__ Wqd) {
  int idx = blockIdx.x*256 + threadIdx.x;   // 319488 total
  if (idx >= 319488) return;
  int tensor = idx / 159744;
  int r = idx % 159744;
  int b  = r / 19968;
  int r2 = r % 19968;
  int o  = r2 / 104, i = r2 % 104;
  ushort* wb = (ushort*)(ws + WS_WB16);
  ushort v = 0;
  if (i < 96) {
    const float* Wq = tensor ? Wqd : Wqu;
    const float* s  = ws + (tensor ? WS_SD : WS_SU);
    v = f2bf(Wq[o*96 + i] * s[b*96 + i]);
  }
  wb[idx] = v;
}

// ---------------- qkv GEMM via MFMA + fused slab epilogue ----------------
__global__ __launch_bounds__(256) void qkv_gemm(float* __restrict__ ws,
    const float* __restrict__ xu, const float* __restrict__ xd) {
  __shared__ __align__(16) ushort QL[16640];   // 33280 B
  ushort* Bl = QL;                 // [64][104] u16 = 6656
  ushort* Ah = QL + 6656;          // [96][104] u16 = 9984
  int blk = blockIdx.x;                 // 2 tensor * 8 b * 128 h * 2 wh
  int tensor = blk >> 11;
  int rem = blk & 2047;
  int b = rem >> 8;
  int r2 = rem & 255;
  int nt = r2 >> 1;                     // h
  int wh = r2 & 1;                      // 64-col half
  int n0 = nt*128 + wh*64;
  const float* x = (tensor ? xd : xu) + (size_t)b*NM;
  const ushort* wb = (const ushort*)(ws + WS_WB16) + (size_t)(tensor*8 + b)*19968;
  const float* bp = ws + (tensor ? WS_BPD : WS_BPU) + b*192;
  ushort* outq16 = (ushort*)(ws + WS_QKV16) + (tensor ? QKV16_D : 0) + (size_t)b*NCO*NN;
  ushort* slab = (ushort*)(ws + WS_SLABS);
  const int t = threadIdx.x;
  const int wv = t >> 6, lid = t & 63, l15 = lid & 15, l4 = lid >> 4;

  // stage B: X^T bf16 [64][104]; 768 tasks (i2 0..47, n4 0..15)
  for (int it = 0; it < 3; it++) {
    int idx = t + it*256;
    int i2 = (idx & 7) | ((idx >> 7) << 3);
    int n4 = (idx >> 3) & 15;
    const float* r0 = x + (size_t)(2*i2)*NN + n0 + n4*4;
    float4 a0 = *(const float4*)r0;
    float4 a1 = *(const float4*)(r0 + NN);
    uint p0 = (uint)f2bf(a0.x) | ((uint)f2bf(a1.x) << 16);
    uint p1 = (uint)f2bf(a0.y) | ((uint)f2bf(a1.y) << 16);
    uint p2 = (uint)f2bf(a0.z) | ((uint)f2bf(a1.z) << 16);
    uint p3 = (uint)f2bf(a0.w) | ((uint)f2bf(a1.w) << 16);
    ushort* base = &Bl[(size_t)(n4*4)*104 + 2*i2];
    *(uint*)(base)           = p0;
    *(uint*)(base + 104)     = p1;
    *(uint*)(base + 208)     = p2;
    *(uint*)(base + 312)     = p3;
  }
  // stage A half 0 (W' rows 0..95): 1248 uint4 linear copy
  for (int it = 0; it < 5; it++) {
    int idx = t + it*256;
    if (idx < 1248) ((uint4*)Ah)[idx] = ((const uint4*)wb)[idx];
  }
  __syncthreads();

  // hoist B fragments (wave wv owns cols wv*16..wv*16+15)
  bf16x8 bfr[3];
  #pragma unroll
  for (int s = 0; s < 3; s++)
    bfr[s] = ldfrag(&Bl[(wv*16 + l15)*104 + s*32 + l4*8]);

  f32x4 z4 = {0.f,0.f,0.f,0.f};
  f32x4 acc[12];
  #pragma unroll
  for (int mt = 0; mt < 12; mt++) acc[mt] = z4;
  // half 0: output rows 0..95
  #pragma unroll
  for (int s = 0; s < 3; s++) {
    #pragma unroll
    for (int mt = 0; mt < 6; mt++) {
      bf16x8 a = ldfrag(&Ah[(mt*16 + l15)*104 + s*32 + l4*8]);
      acc[mt] = __builtin_amdgcn_mfma_f32_16x16x32_bf16(a, bfr[s], acc[mt], 0, 0, 0);
    }
  }
  __syncthreads();
  // stage A half 1 (W' rows 96..191)
  for (int it = 0; it < 5; it++) {
    int idx = t + it*256;
    if (idx < 1248) ((uint4*)Ah)[idx] = ((const uint4*)wb)[1248 + idx];
  }
  __syncthreads();
  #pragma unroll
  for (int s = 0; s < 3; s++) {
    #pragma unroll
    for (int mt = 0; mt < 6; mt++) {
      bf16x8 a = ldfrag(&Ah[(mt*16 + l15)*104 + s*32 + l4*8]);
      acc[6+mt] = __builtin_amdgcn_mfma_f32_16x16x32_bf16(a, bfr[s], acc[6+mt], 0, 0, 0);
    }
  }
  __syncthreads();       // all LDS reads done; reuse QL as C bounce [192][72] u16
  ushort* Cl = QL;
  #pragma unroll
  for (int mt = 0; mt < 12; mt++) {
    #pragma unroll
    for (int r = 0; r < 4; r++) {
      int o = mt*16 + l4*4 + r;
      Cl[o*72 + wv*16 + l15] = f2bf(acc[mt][r] + bp[o]);
    }
  }
  __syncthreads();
  // (1) qkv16 store, 96 channels {64..127, 160..191}: 768 uint4
  for (int it = 0; it < 3; it++) {
    int idx = t + it*256;
    int lr = idx >> 3, ch = idx & 7;
    int o = (lr < 64) ? (64 + lr) : (96 + lr);
    *(uint4*)(outq16 + (size_t)o*NN + n0 + ch*8) = *(const uint4*)&Cl[o*72 + ch*8];
  }
  // (2) Q/K h- and w-slabs (PACKED 32c rows): 128 tasks
  if (t < 128) {
    int axis = t >> 6, w = t & 63;
    ushort* dstq = slab + (tensor ? (axis ? OFF_KW : OFF_KH) : (axis ? OFF_QW : OFF_QH));
    size_t o = axis ? ((size_t)(b*128 + nt)*128 + wh*64 + w)*32
                    : ((size_t)(b*128 + wh*64 + w)*128 + nt)*32;
    uint uu[16];
    #pragma unroll
    for (int k = 0; k < 16; k++) {
      ushort a0 = Cl[(axis*32 + 2*k)*72 + w];
      ushort a1 = Cl[(axis*32 + 2*k + 1)*72 + w];
      uu[k] = (uint)a0 | ((uint)a1 << 16);
    }
    *(uint4*)(dstq + o)      = make_uint4(uu[0],uu[1],uu[2],uu[3]);
    *(uint4*)(dstq + o + 8)  = make_uint4(uu[4],uu[5],uu[6],uu[7]);
    *(uint4*)(dstq + o + 16) = make_uint4(uu[8],uu[9],uu[10],uu[11]);
    *(uint4*)(dstq + o + 24) = make_uint4(uu[12],uu[13],uu[14],uu[15]);
  }
  // (3) VW slab (ch 128..159, PACKED 128w rows): 256 uint4 tasks
  {
    ushort* dstv = slab + (tensor ? OFF_VWD : OFF_VWU);
    int c = t >> 3, ch = t & 7;
    *(uint4*)(dstv + ((size_t)(b*128 + nt)*32 + c)*128 + wh*64 + ch*8) =
        *(const uint4*)&Cl[(128 + c)*72 + ch*8];
  }
}

// ---------------- prep: VH slabs only (ch 96..127 -> [b][w][32c][128h] packed) ----------------
__global__ __launch_bounds__(256) void qkv_prep(float* __restrict__ ws) {
  __shared__ __align__(16) ushort Br[16*1320];   // [16c][33h][40w] c-stride 1320
  int bid = blockIdx.x;                           // 2 tensor * 2cb * 8b * 4hb * 4wb = 512
  int tensor = bid >> 8;
  int r = bid & 255;
  int cb = r >> 7, b = (r >> 4) & 7, hb = (r >> 2) & 3, wb = r & 3;
  const ushort* qkv16 = (const ushort*)(ws + WS_QKV16);
  const ushort* src = qkv16 + (tensor ? QKV16_D : 0)
                    + (size_t)b*NCO*NN + (size_t)(96 + cb*16)*NN;
  ushort* dst = (ushort*)(ws + WS_SLABS) + (tensor ? OFF_VHD : OFF_VHU);
  int t = threadIdx.x;
  for (int k = 0; k < 8; k++) {
    int idx = t + k*256;                          // 2048 = 16c*32h*4(w8)
    int c = idx >> 7, h = (idx >> 2) & 31, w8 = idx & 3;
    uint4 v = *(const uint4*)(src + (size_t)c*NN + (size_t)(hb*32 + h)*NWID + wb*32 + w8*8);
    *(uint4*)&Br[c*1320 + h*40 + w8*8] = v;
  }
  __syncthreads();
  for (int k = 0; k < 2; k++) {
    int idx = t + k*256;                          // 512 = 32w*16c
    int w = idx >> 4, c = idx & 15;
    uint uu[16];
    #pragma unroll
    for (int hh = 0; hh < 16; hh++) {
      ushort a0 = Br[c*1320 + (2*hh)*40 + w];
      ushort a1 = Br[c*1320 + (2*hh+1)*40 + w];
      uu[hh] = (uint)a0 | ((uint)a1 << 16);
    }
    size_t o = ((size_t)(b*128 + wb*32 + w)*32 + cb*16 + c)*128 + hb*32;
    *(uint4*)(dst + o)      = make_uint4(uu[0],uu[1],uu[2],uu[3]);
    *(uint4*)(dst + o + 8)  = make_uint4(uu[4],uu[5],uu[6],uu[7]);
    *(uint4*)(dst + o + 16) = make_uint4(uu[8],uu[9],uu[10],uu[11]);
    *(uint4*)(dst + o + 24) = make_uint4(uu[12],uu[13],uu[14],uu[15]);
  }
}

// ---------------- fused spatial attention (blocks 0..2047) + channel scores (2048..2559) ----------------
__global__ __launch_bounds__(256) void attn_both(float* __restrict__ ws,
    const float* __restrict__ xu, const float* __restrict__ xd,
    float* __restrict__ out, const float* __restrict__ sch, const float* __restrict__ scw) {
  __shared__ __align__(16) ushort SMEM[36352];   // 72704 B
  __shared__ float m1s[128];
  const int t = threadIdx.x;

  if (blockIdx.x >= 2048) {
    // ===== attn_c1 via MFMA: S[c][d] += sum_n Q[c,n] K[d,n] over 256-col chunk =====
    ushort* qs16 = SMEM;            // [32][264] bf16
    ushort* ks16 = SMEM + 8448;     // [32][264] bf16
    int bid = blockIdx.x - 2048;
    int b = bid >> 6, chunk = bid & 63;
    int n0 = chunk * 256;
    const ushort* qkv16 = (const ushort*)(ws + WS_QKV16);
    const ushort* qp = qkv16 + ((size_t)b*NCO + 64)*NN + n0;
    const ushort* kp = qkv16 + QKV16_D + ((size_t)b*NCO + 64)*NN + n0;
    for (int it = 0; it < 8; it++) {
      int idx = t + it*256;
      int mat = idx >> 10;
      int r = idx & 1023;
      int c = r >> 5, n8 = r & 31;
      const ushort* src = (mat ? kp : qp) + (size_t)c*NN + n8*8;
      ushort* dst = (mat ? ks16 : qs16) + c*264 + n8*8;
      *(uint4*)dst = *(const uint4*)src;
    }
    __syncthreads();
    const int wv = t >> 6, lid = t & 63, l15 = lid & 15, l4 = lid >> 4;
    const int cr = wv >> 1, dc = wv & 1;
    f32x4 z4 = {0.f,0.f,0.f,0.f};
    f32x4 acc = z4;
    #pragma unroll
    for (int ks = 0; ks < 8; ks++) {
      bf16x8 a = ldfrag(&qs16[(cr*16 + l15)*264 + ks*32 + l4*8]);
      bf16x8 bq = ldfrag(&ks16[(dc*16 + l15)*264 + ks*32 + l4*8]);
      acc = __builtin_amdgcn_mfma_f32_16x16x32_bf16(a, bq, acc, 0, 0, 0);
    }
    #pragma unroll
    for (int r = 0; r < 4; r++) {
      int c = cr*16 + l4*4 + r;
      int d = dc*16 + l15;
      atomicAdd(&ws[WS_SC + b*1024 + c*32 + d], acc[r]);
    }
    return;
  }

  // ===== spatial attention (AXIS 0 = h, 1 = w) =====
  ushort* Qs  = SMEM;            // [128][40]
  ushort* Ks  = SMEM + 5120;     // [128][40]
  ushort* Vds = SMEM + 10240;    // [32][136]
  ushort* Vus = SMEM + 14592;    // [32][136]
  ushort* Pl  = SMEM + 18944;    // [128][136]
  const int AXIS = blockIdx.x >> 10;
  const int rem = blockIdx.x & 1023;
  const int b = rem >> 7, p2 = rem & 127;
  const int wv = t >> 6, lid = t & 63, l15 = lid & 15, l4 = lid >> 4;
  const ushort* slab = (const ushort*)(ws + WS_SLABS);
  const ushort* qsrc  = slab + (AXIS ? OFF_QW : OFF_QH) + (size_t)(b*128 + p2)*4096;
  const ushort* ksrc  = slab + (AXIS ? OFF_KW : OFF_KH) + (size_t)(b*128 + p2)*4096;
  const ushort* vdsrc = slab + (AXIS ? OFF_VWD : OFF_VHD) + (size_t)(b*128 + p2)*4096;
  const ushort* vusrc = slab + (AXIS ? OFF_VWU : OFF_VHU) + (size_t)(b*128 + p2)*4096;
  for (int i = t; i < 2048; i += 256) {
    if (i < 512) {
      int row = i >> 2, q = i & 3;
      *(uint4*)&Qs[row*40 + q*8] = *(const uint4*)(qsrc + row*32 + q*8);
    } else if (i < 1024) {
      int j = i - 512, row = j >> 2, q = j & 3;
      *(uint4*)&Ks[row*40 + q*8] = *(const uint4*)(ksrc + row*32 + q*8);
    } else if (i < 1536) {
      int j = i - 1024, row = j >> 4, ch = j & 15;
      *(uint4*)&Vds[row*136 + ch*8] = *(const uint4*)(vdsrc + row*128 + ch*8);
    } else {
      int j = i - 1536, row = j >> 4, ch = j & 15;
      *(uint4*)&Vus[row*136 + ch*8] = *(const uint4*)(vusrc + row*128 + ch*8);
    }
  }
  const float sc = (AXIS ? scw : sch)[0];
  const int cbas = AXIS ? 32 : 0;
  float ruv0 = ws[WS_RU + b*96 + cbas + l15];
  float ruv1 = ws[WS_RU + b*96 + cbas + 16 + l15];
  float rdv0 = ws[WS_RD + b*96 + cbas + l15];
  float rdv1 = ws[WS_RD + b*96 + cbas + 16 + l15];
  __syncthreads();

  f32x4 z4 = {0.f,0.f,0.f,0.f};
  f32x4 s1[2][8];
  // ---- S1[i][j] = sum_c Q[i][c] K[j][c] ----
  {
    bf16x8 bfr[8];
    #pragma unroll
    for (int tj = 0; tj < 8; tj++) bfr[tj] = ldfrag(&Ks[(tj*16 + l15)*40 + l4*8]);
    #pragma unroll
    for (int ti = 0; ti < 2; ti++) {
      bf16x8 a = ldfrag(&Qs[((2*wv+ti)*16 + l15)*40 + l4*8]);
      #pragma unroll
      for (int tj = 0; tj < 8; tj++)
        s1[ti][tj] = __builtin_amdgcn_mfma_f32_16x16x32_bf16(a, bfr[tj], z4, 0, 0, 0);
    }
  }
  // ---- row softmax stats over j; write RAW exp to Pl; keep 1/l1 in regs ----
  float il1r[2][4];
  #pragma unroll
  for (int ti = 0; ti < 2; ti++) {
    #pragma unroll
    for (int r = 0; r < 4; r++) {
      float mx = -3.0e38f;
      #pragma unroll
      for (int tj = 0; tj < 8; tj++) { float v = s1[ti][tj][r]*sc; s1[ti][tj][r] = v; mx = fmaxf(mx, v); }
      mx = fmaxf(mx, __shfl_xor(mx, 1)); mx = fmaxf(mx, __shfl_xor(mx, 2));
      mx = fmaxf(mx, __shfl_xor(mx, 4)); mx = fmaxf(mx, __shfl_xor(mx, 8));
      float sm = 0.f;
      #pragma unroll
      for (int tj = 0; tj < 8; tj++) { float e = __expf(s1[ti][tj][r] - mx); s1[ti][tj][r] = e; sm += e; }
      sm += __shfl_xor(sm, 1); sm += __shfl_xor(sm, 2); sm += __shfl_xor(sm, 4); sm += __shfl_xor(sm, 8);
      int row = 32*wv + ti*16 + l4*4 + r;
      if (l15 == 0) m1s[row] = mx + __logf(sm);   // folded for AXIS=0 pass-2
      il1r[ti][r] = __fdividef(1.f, sm);
      #pragma unroll
      for (int tj = 0; tj < 8; tj++) Pl[row*136 + tj*16 + l15] = f2bf(s1[ti][tj][r]);
    }
  }
  __syncthreads();
  // ---- PV1 (unnormalized), then rescale by reg-resident 1/l1 ----
  f32x4 o1[2][2] = {{z4,z4},{z4,z4}};
  #pragma unroll
  for (int ks = 0; ks < 4; ks++) {
    bf16x8 bv0 = ldfrag(&Vds[l15*136 + ks*32 + l4*8]);
    bf16x8 bv1 = ldfrag(&Vds[(16 + l15)*136 + ks*32 + l4*8]);
    #pragma unroll
    for (int mt = 0; mt < 2; mt++) {
      bf16x8 a = ldfrag(&Pl[((2*wv+mt)*16 + l15)*136 + ks*32 + l4*8]);
      o1[mt][0] = __builtin_amdgcn_mfma_f32_16x16x32_bf16(a, bv0, o1[mt][0], 0, 0, 0);
      o1[mt][1] = __builtin_amdgcn_mfma_f32_16x16x32_bf16(a, bv1, o1[mt][1], 0, 0, 0);
    }
  }
  #pragma unroll
  for (int mt = 0; mt < 2; mt++)
    #pragma unroll
    for (int nt = 0; nt < 2; nt++)
      #pragma unroll
      for (int r = 0; r < 4; r++)
        o1[mt][nt][r] *= il1r[mt][r];
  // ---- S2 = S1^T via mfma(K, Q) ----
  {
    bf16x8 bq[8];
    #pragma unroll
    for (int it = 0; it < 8; it++) bq[it] = ldfrag(&Qs[(it*16 + l15)*40 + l4*8]);
    #pragma unroll
    for (int tjt = 0; tjt < 2; tjt++) {
      bf16x8 a = ldfrag(&Ks[((2*wv+tjt)*16 + l15)*40 + l4*8]);
      #pragma unroll
      for (int it = 0; it < 8; it++)
        s1[tjt][it] = __builtin_amdgcn_mfma_f32_16x16x32_bf16(a, bq[it], z4, 0, 0, 0);
    }
  }
  // ---- pass-2 softmax ----
  float il2r[2][4];
  if (AXIS == 1) {
    #pragma unroll
    for (int tjt = 0; tjt < 2; tjt++) {
      #pragma unroll
      for (int r = 0; r < 4; r++) {
        float mx = -3.0e38f;
        #pragma unroll
        for (int it = 0; it < 8; it++) { float v = s1[tjt][it][r]*sc; s1[tjt][it][r] = v; mx = fmaxf(mx, v); }
        mx = fmaxf(mx, __shfl_xor(mx, 1)); mx = fmaxf(mx, __shfl_xor(mx, 2));
        mx = fmaxf(mx, __shfl_xor(mx, 4)); mx = fmaxf(mx, __shfl_xor(mx, 8));
        float sm = 0.f;
        #pragma unroll
        for (int it = 0; it < 8; it++) { float e = __expf(s1[tjt][it][r] - mx); s1[tjt][it][r] = e; sm += e; }
        sm += __shfl_xor(sm, 1); sm += __shfl_xor(sm, 2); sm += __shfl_xor(sm, 4); sm += __shfl_xor(sm, 8);
        il2r[tjt][r] = __fdividef(1.f, sm);
      }
    }
  } else {
    float mi[8];
    #pragma unroll
    for (int it = 0; it < 8; it++) mi[it] = m1s[it*16 + l15];
    #pragma unroll
    for (int tjt = 0; tjt < 2; tjt++)
      #pragma unroll
      for (int it = 0; it < 8; it++)
        #pragma unroll
        for (int r = 0; r < 4; r++)
          s1[tjt][it][r] = __expf(s1[tjt][it][r]*sc - mi[it]);
    il2r[0][0] = il2r[0][1] = il2r[0][2] = il2r[0][3] = 1.f;
    il2r[1][0] = il2r[1][1] = il2r[1][2] = il2r[1][3] = 1.f;
  }
  __syncthreads();
  #pragma unroll
  for (int tjt = 0; tjt < 2; tjt++)
    #pragma unroll
    for (int r = 0; r < 4; r++) {
      int row = 32*wv + tjt*16 + l4*4 + r;
      #pragma unroll
      for (int it = 0; it < 8; it++) Pl[row*136 + it*16 + l15] = f2bf(s1[tjt][it][r]);
    }
  __syncthreads();
  // ---- PV2 (unnormalized for AXIS=1), then rescale ----
  f32x4 o2[2][2] = {{z4,z4},{z4,z4}};
  #pragma unroll
  for (int ks = 0; ks < 4; ks++) {
    bf16x8 bv0 = ldfrag(&Vus[l15*136 + ks*32 + l4*8]);
    bf16x8 bv1 = ldfrag(&Vus[(16 + l15)*136 + ks*32 + l4*8]);
    #pragma unroll
    for (int mt = 0; mt < 2; mt++) {
      bf16x8 a = ldfrag(&Pl[((2*wv+mt)*16 + l15)*136 + ks*32 + l4*8]);
      o2[mt][0] = __builtin_amdgcn_mfma_f32_16x16x32_bf16(a, bv0, o2[mt][0], 0, 0, 0);
      o2[mt][1] = __builtin_amdgcn_mfma_f32_16x16x32_bf16(a, bv1, o2[mt][1], 0, 0, 0);
    }
  }
  #pragma unroll
  for (int mt = 0; mt < 2; mt++)
    #pragma unroll
    for (int nt = 0; nt < 2; nt++)
      #pragma unroll
      for (int r = 0; r < 4; r++)
        o2[mt][nt][r] *= il2r[mt][r];
  __syncthreads();   // reuse Pl as fp32 stage [32][132]
  float* St = (float*)Pl;
  #pragma unroll
  for (int mt = 0; mt < 2; mt++)
    #pragma unroll
    for (int nt = 0; nt < 2; nt++) {
      float ru = nt ? ruv1 : ruv0;
      float rd = nt ? rdv1 : rdv0;
      float4 vv;
      vv.x = o1[mt][nt][0]*ru + o2[mt][nt][0]*rd;
      vv.y = o1[mt][nt][1]*ru + o2[mt][nt][1]*rd;
      vv.z = o1[mt][nt][2]*ru + o2[mt][nt][2]*rd;
      vv.w = o1[mt][nt][3]*ru + o2[mt][nt][3]*rd;
      *(float4*)&St[(nt*16 + l15)*132 + (2*wv+mt)*16 + l4*4] = vv;
    }
  __syncthreads();
  if (AXIS == 1) {
    for (int k = 0; k < 4; k++) {
      int idx = t + k*256;
      int c = idx >> 5, p4 = idx & 31;
      float4 v = *(const float4*)&St[c*132 + p4*4];
      float ca = ws[WS_CADD + b*96 + 32 + c];
      size_t off = ((size_t)(b*NC + 32 + c)*NH + p2)*NWID + p4*4;
      float4 a = *(const float4*)(xu + off);
      float4 dd = *(const float4*)(xd + off);
      v.x += ca + a.x + dd.x; v.y += ca + a.y + dd.y;
      v.z += ca + a.z + dd.z; v.w += ca + a.w + dd.w;
      *(float4*)(out + off) = v;
    }
  } else {
    ushort* oh16 = (ushort*)(ws + WS_OH);
    for (int k = 0; k < 2; k++) {
      int idx = t + k*256;               // 512 = 32c * 16 p8
      int c = idx >> 4, p8 = idx & 15;
      const float* src = &St[c*132 + p8*8];
      uint4 pk;
      pk.x = (uint)f2bf(src[0]) | ((uint)f2bf(src[1]) << 16);
      pk.y = (uint)f2bf(src[2]) | ((uint)f2bf(src[3]) << 16);
      pk.z = (uint)f2bf(src[4]) | ((uint)f2bf(src[5]) << 16);
      pk.w = (uint)f2bf(src[6]) | ((uint)f2bf(src[7]) << 16);
      *(uint4*)(oh16 + ((size_t)(b*128 + p2)*32 + c)*128 + p8*8) = pk;
    }
  }
}

// ---------------- fused tail: merge_h (blocks 0..4095) + channel apply (4096..4607) ----------------
__global__ __launch_bounds__(256) void tail_out(float* __restrict__ ws,
    const float* __restrict__ xu, const float* __restrict__ xd,
    float* __restrict__ out, const float* __restrict__ scale_p) {
  int t = threadIdx.x;
  if (blockIdx.x < 4096) {
    // ===== merge_h: OH bf16 staging -> final out (ch 0..31) =====
    __shared__ float T[32][33];
    int bid = blockIdx.x;
    int b = bid >> 9, c = (bid >> 4) & 31, ht = (bid >> 2) & 3, wt = bid & 3;
    const ushort* oh16 = (const ushort*)(ws + WS_OH);
    {
      int w = t >> 3, hq = t & 7;
      uint2 v = *(const uint2*)(oh16 + ((size_t)(b*128 + wt*32 + w)*32 + c)*128 + ht*32 + hq*4);
      T[w][hq*4+0] = bf2f((ushort)(v.x & 0xffff));
      T[w][hq*4+1] = bf2f((ushort)(v.x >> 16));
      T[w][hq*4+2] = bf2f((ushort)(v.y & 0xffff));
      T[w][hq*4+3] = bf2f((ushort)(v.y >> 16));
    }
    __syncthreads();
    {
      int h = t >> 3, w4 = t & 7;
      float ca = ws[WS_CADD + b*96 + c];
      size_t off = ((size_t)(b*NC + c)*NH + ht*32 + h)*NWID + wt*32 + w4*4;
      float4 a = *(const float4*)(xu + off);
      float4 d = *(const float4*)(xd + off);
      float4 v;
      v.x = T[w4*4+0][h] + ca + a.x + d.x;
      v.y = T[w4*4+1][h] + ca + a.y + d.y;
      v.z = T[w4*4+2][h] + ca + a.z + d.z;
      v.w = T[w4*4+3][h] + ca + a.w + d.w;
      *(float4*)(out + off) = v;
    }
    return;
  }
  // ===== channel attention: softmax + apply + epilogue (ch 64..95) =====
  __shared__ float scl[32][33];
  __shared__ float AsT[32][36];
  __shared__ float ruL[32], rdL[32], caL[32];
  int bid = blockIdx.x - 4096;
  int b = bid >> 6, chunk = bid & 63;
  for (int r = 0; r < 4; r++) {
    int idx = t + r*256;
    int c = idx >> 5, d = idx & 31;
    scl[c][d] = ws[WS_SC + b*1024 + idx];
  }
  if (t < 32) {
    ruL[t] = ws[WS_RU + b*96 + 64 + t];
    rdL[t] = ws[WS_RD + b*96 + 64 + t];
    caL[t] = ws[WS_CADD + b*96 + 64 + t];
  }
  __syncthreads();
  if (t < 32) {
    float sc = scale_p[0];
    float row[32];
    float m = -3.0e38f;
    for (int d = 0; d < 32; d++) { row[d] = scl[t][d] * sc; m = fmaxf(m, row[d]); }
    float s = 0.f;
    for (int d = 0; d < 32; d++) { row[d] = __expf(row[d] - m); s += row[d]; }
    float inv = 1.f / s;
    for (int d = 0; d < 32; d++) AsT[d][t] = row[d]*inv;
  }
  __syncthreads();
  int n = chunk*256 + t;
  const ushort* qkv16 = (const ushort*)(ws + WS_QKV16);
  const ushort* vdp = qkv16 + QKV16_D + ((size_t)b*NCO + 160)*NN + n;
  const ushort* vup = qkv16 + ((size_t)b*NCO + 160)*NN + n;
  float acc1[32], acc2[32];
  #pragma unroll
  for (int c2 = 0; c2 < 32; c2++) { acc1[c2]=0.f; acc2[c2]=0.f; }
  for (int d = 0; d < 32; d++) {
    float vd = bf2f(vdp[(size_t)d*NN]);
    float vu = bf2f(vup[(size_t)d*NN]);
    #pragma unroll
    for (int c4 = 0; c4 < 8; c4++) {
      float4 av = *(const float4*)&AsT[d][c4*4];
      acc1[c4*4+0] += av.x*vd; acc2[c4*4+0] += av.x*vu;
      acc1[c4*4+1] += av.y*vd; acc2[c4*4+1] += av.y*vu;
      acc1[c4*4+2] += av.z*vd; acc2[c4*4+2] += av.z*vu;
      acc1[c4*4+3] += av.w*vd; acc2[c4*4+3] += av.w*vu;
    }
  }
  size_t base = ((size_t)(b*NC) + 64)*NN + n;
  #pragma unroll
  for (int c2 = 0; c2 < 32; c2++) {
    size_t off = base + (size_t)c2*NN;
    out[off] = acc1[c2]*ruL[c2] + acc2[c2]*rdL[c2] + caL[c2] + xu[off] + xd[off];
  }
}

extern "C" void kernel_launch(void* const* d_in, const int* in_sizes, int n_in,
                              void* d_out, int out_size, void* d_ws, size_t ws_size,
                              hipStream_t stream) {
  (void)in_sizes; (void)n_in; (void)out_size; (void)ws_size;
  const float* xu   = (const float*)d_in[0];
  const float* xd   = (const float*)d_in[1];
  const float* nwu  = (const float*)d_in[2];
  const float* nbu  = (const float*)d_in[3];
  const float* m1wu = (const float*)d_in[4];
  const float* m1bu = (const float*)d_in[5];
  const float* m2wu = (const float*)d_in[6];
  const float* m2bu = (const float*)d_in[7];
  const float* nwd  = (const float*)d_in[8];
  const float* nbd  = (const float*)d_in[9];
  const float* m1wd = (const float*)d_in[10];
  const float* m1bd = (const float*)d_in[11];
  const float* m2wd = (const float*)d_in[12];
  const float* m2bd = (const float*)d_in[13];
  const float* Wqu  = (const float*)d_in[14];
  const float* bqu  = (const float*)d_in[15];
  const float* Wqd  = (const float*)d_in[16];
  const float* bqd  = (const float*)d_in[17];
  const float* sch  = (const float*)d_in[18];
  const float* scw  = (const float*)d_in[19];
  const float* scc  = (const float*)d_in[20];
  float* ws  = (float*)d_ws;
  float* out = (float*)d_out;

  hipMemsetAsync(d_ws, 0, 8224*sizeof(float), stream);
  reduce_stats<<<1024, 256, 0, stream>>>(xu, xd, ws);
  compute_params<<<1, 256, 0, stream>>>(ws, nwu, nbu, m1wu, m1bu, m2wu, m2bu,
                                        nwd, nbd, m1wd, m1bd, m2wd, m2bd,
                                        Wqu, bqu, Wqd, bqd);
  compute_wprime<<<1248, 256, 0, stream>>>(ws, Wqu, Wqd);
  qkv_gemm<<<4096, 256, 0, stream>>>(ws, xu, xd);
  qkv_prep<<<512, 256, 0, stream>>>(ws);
  attn_both<<<2560, 256, 0, stream>>>(ws, xu, xd, out, sch, scw);
  tail_out<<<4608, 256, 0, stream>>>(ws, xu, xd, out, scc);
}